// Round 5
// baseline (5521.412 us; speedup 1.0000x reference)
//
#include <hip/hip_runtime.h>
#include <hip/hip_bf16.h>
#include <math.h>

#define BBATCH 256
#define DMODEL 512
#define NHEAD 4
#define DHEAD 128
#define DFFN 1024
#define KCB 8192
#define VEPS 0.02f
#define NROWS 12544
#define NSPLIT 64   // 8192 / 128 code tiles

typedef __attribute__((ext_vector_type(8))) short short8v;   // 8 bf16 in 4 VGPRs
typedef __attribute__((ext_vector_type(4))) float f32x4;

// ---------------- conv weight transform: wc[(k*512+di)*512 + do] = cw[do][di][k]
__global__ __launch_bounds__(256) void k_wconv(const float* __restrict__ cw,
                                               float* __restrict__ wc) {
    int idx = blockIdx.x * 256 + threadIdx.x;
    if (idx >= 3 * DMODEL * DMODEL) return;
    int dout = idx & (DMODEL - 1);
    int rest = idx >> 9;
    int di = rest & (DMODEL - 1);
    int k = rest >> 9;
    wc[idx] = cw[((size_t)dout * DMODEL + di) * 3 + k];
}

// ---------------- fp32 SGEMM, 128x128 tile, 8x8 micro-tile (2x2 of 4x4), BK=16.
// C[M][N] = act(A[M][K] @ Bm[K][N] + bias). ACT: 0 none, 1 exact GELU (fp64), 2 relu.
// CONV: A rows gathered via causal-half-downsample frame map (k = tap*512 + channel).
template <int ACT, int CONV>
__global__ __launch_bounds__(256) void k_gemm32(const float* __restrict__ A, int lda,
                                                const float* __restrict__ Bm, int ldb,
                                                const float* __restrict__ bias,
                                                float* __restrict__ C, int ldc,
                                                int K, int Tin, int Tout) {
    __shared__ __align__(16) float As[16][132];
    __shared__ __align__(16) float Bs[16][132];
    int tid = threadIdx.x;
    int tx = tid & 15, ty = tid >> 4;
    int m0 = blockIdx.y * 128, n0 = blockIdx.x * 128;

    // A staging row base for the 2 rows this thread covers (mm = (tid+r*256)>>2)
    size_t abase[2]; int att[2];
#pragma unroll
    for (int r = 0; r < 2; r++) {
        int idx = tid + r * 256;
        int mm = idx >> 2;
        int m = m0 + mm;
        if (CONV) {
            int b = m / Tout, tt = m - b * Tout;
            abase[r] = (size_t)b * Tin * DMODEL;
            att[r] = 2 * tt - 2;
        } else {
            abase[r] = (size_t)m * lda;
            att[r] = 0;
        }
    }

    float acc[8][8];
#pragma unroll
    for (int i = 0; i < 8; i++)
#pragma unroll
        for (int j = 0; j < 8; j++) acc[i][j] = 0.0f;

    for (int k0 = 0; k0 < K; k0 += 16) {
        // ---- stage A: 128 rows x 16 k; thread loads float4 along k, scatters to As[k][m]
#pragma unroll
        for (int r = 0; r < 2; r++) {
            int idx = tid + r * 256;
            int mm = idx >> 2, kq = idx & 3;
            const float* ap;
            if (CONV) {
                int f = att[r] + (k0 >> 9);
                if (f < 0) f = 0;
                ap = A + abase[r] + (size_t)f * DMODEL + (k0 & 511) + kq * 4;
            } else {
                ap = A + abase[r] + k0 + kq * 4;
            }
            float4 v = *(const float4*)ap;
            As[kq * 4 + 0][mm] = v.x;
            As[kq * 4 + 1][mm] = v.y;
            As[kq * 4 + 2][mm] = v.z;
            As[kq * 4 + 3][mm] = v.w;
        }
        // ---- stage B: 16 k x 128 n; coalesced float4, direct float4 LDS write
#pragma unroll
        for (int r = 0; r < 2; r++) {
            int idx = tid + r * 256;
            int kb = idx >> 5, nn = (idx & 31) * 4;
            *(float4*)&Bs[kb][nn] = *(const float4*)&Bm[(size_t)(k0 + kb) * ldb + n0 + nn];
        }
        __syncthreads();
#pragma unroll
        for (int kk = 0; kk < 16; kk++) {
            float4 a0 = *(const float4*)&As[kk][ty * 4];
            float4 a1 = *(const float4*)&As[kk][64 + ty * 4];
            float4 b0 = *(const float4*)&Bs[kk][tx * 4];
            float4 b1 = *(const float4*)&Bs[kk][64 + tx * 4];
            float av[8] = {a0.x, a0.y, a0.z, a0.w, a1.x, a1.y, a1.z, a1.w};
            float bv[8] = {b0.x, b0.y, b0.z, b0.w, b1.x, b1.y, b1.z, b1.w};
#pragma unroll
            for (int i = 0; i < 8; i++)
#pragma unroll
                for (int j = 0; j < 8; j++) acc[i][j] = fmaf(av[i], bv[j], acc[i][j]);
        }
        __syncthreads();
    }

#pragma unroll
    for (int i = 0; i < 8; i++) {
        int row = m0 + (i < 4 ? ty * 4 + i : 64 + ty * 4 + (i - 4));
#pragma unroll
        for (int j = 0; j < 8; j++) {
            int col = n0 + (j < 4 ? tx * 4 + j : 64 + tx * 4 + (j - 4));
            float x;
            if (ACT == 1) {
                double v = (double)acc[i][j] + (double)bias[col];
                v = 0.5 * v * (1.0 + erf(v * 0.7071067811865476));
                x = (float)v;
            } else {
                x = acc[i][j] + bias[col];
                if (ACT == 2) x = x > 0.0f ? x : 0.0f;
            }
            C[(size_t)row * ldc + col] = x;
        }
    }
}

// ---------------- broadcast helper: uniform lane read
__device__ __forceinline__ float lanebc(float x, int l) {
    return __int_as_float(__builtin_amdgcn_readlane(__float_as_int(x), l));
}

// ---------------- attention: one block per (h, b); 4 waves, rows i%4==wave.
__global__ __launch_bounds__(256) void k_attn(const float* q,
                                              const float* __restrict__ k,
                                              const float* __restrict__ v,
                                              float* out, int T) {
    __shared__ float Ks[98][129];
    int h = blockIdx.x, b = blockIdx.y;
    int tid = threadIdx.x;
    int lane = tid & 63;
    int wave = tid >> 6;
    size_t base = ((size_t)b * T) * DMODEL + (size_t)h * DHEAD;

    for (int idx = tid; idx < T * DHEAD; idx += 256) {
        int j = idx >> 7, d = idx & 127;
        Ks[j][d] = k[base + (size_t)j * DMODEL + d];
    }
    __syncthreads();

    const float SCALE = 0.08838834764831845f;
    for (int i = wave; i < T; i += 4) {
        float qa = q[base + (size_t)i * DMODEL + lane];
        float qb = q[base + (size_t)i * DMODEL + lane + 64];

        int j1 = lane;
        int j2 = lane + 64;
        int j2c = j2 < T ? j2 : 0;
        bool a0 = (j1 <= i);
        bool a1 = (j2 <= i);

        float s0 = 0.0f, s1 = 0.0f;
#pragma unroll 8
        for (int d = 0; d < 64; d++) {
            float qd = lanebc(qa, d);
            s0 = fmaf(qd, Ks[j1][d], s0);
            s1 = fmaf(qd, Ks[j2c][d], s1);
        }
#pragma unroll 8
        for (int d = 0; d < 64; d++) {
            float qd = lanebc(qb, d);
            s0 = fmaf(qd, Ks[j1][64 + d], s0);
            s1 = fmaf(qd, Ks[j2c][64 + d], s1);
        }
        float s0v = a0 ? s0 * SCALE : -1e30f;
        float s1v = a1 ? s1 * SCALE : -1e30f;

        float m = fmaxf(s0v, s1v);
#pragma unroll
        for (int off = 32; off > 0; off >>= 1) m = fmaxf(m, __shfl_xor(m, off, 64));

        float p0 = a0 ? expf(s0v - m) : 0.0f;
        float p1 = a1 ? expf(s1v - m) : 0.0f;

        float sum = p0 + p1;
#pragma unroll
        for (int off = 32; off > 0; off >>= 1) sum += __shfl_xor(sum, off, 64);
        float inv = 1.0f / sum;

        float o0 = 0.0f, o1 = 0.0f;
        int jmax0 = i < 63 ? i : 63;
        for (int j = 0; j <= jmax0; j++) {
            float pj = lanebc(p0, j);
            const float* vr = v + base + (size_t)j * DMODEL;
            o0 = fmaf(pj, vr[lane], o0);
            o1 = fmaf(pj, vr[lane + 64], o1);
        }
        for (int j = 64; j <= i; j++) {
            float pj = lanebc(p1, j - 64);
            const float* vr = v + base + (size_t)j * DMODEL;
            o0 = fmaf(pj, vr[lane], o0);
            o1 = fmaf(pj, vr[lane + 64], o1);
        }
        out[base + (size_t)i * DMODEL + lane] = o0 * inv;
        out[base + (size_t)i * DMODEL + lane + 64] = o1 * inv;
    }
}

// ---------------- fused residual-add + LayerNorm
__global__ __launch_bounds__(128) void k_ln(const float* __restrict__ resid,
                                            const float* __restrict__ y,
                                            const float* __restrict__ g,
                                            const float* __restrict__ bta,
                                            float* __restrict__ out) {
    int row = blockIdx.x;
    int tid = threadIdx.x;
    size_t off = (size_t)row * DMODEL;
    double t[4];
#pragma unroll
    for (int i = 0; i < 4; i++) {
        int d = tid + i * 128;
        t[i] = (double)resid[off + d] + (double)y[off + d];
    }
    __shared__ double rd[2];
    double s = t[0] + t[1] + t[2] + t[3];
#pragma unroll
    for (int o = 32; o > 0; o >>= 1) s += __shfl_down(s, o, 64);
    if ((tid & 63) == 0) rd[tid >> 6] = s;
    __syncthreads();
    double mean = (rd[0] + rd[1]) * (1.0 / 512.0);
    double vs = 0.0;
#pragma unroll
    for (int i = 0; i < 4; i++) { double dl = t[i] - mean; vs += dl * dl; }
    __syncthreads();
#pragma unroll
    for (int o = 32; o > 0; o >>= 1) vs += __shfl_down(vs, o, 64);
    if ((tid & 63) == 0) rd[tid >> 6] = vs;
    __syncthreads();
    double var = (rd[0] + rd[1]) * (1.0 / 512.0);
    double scale = 1.0 / sqrt(var + 1e-5);
#pragma unroll
    for (int i = 0; i < 4; i++) {
        int d = tid + i * 128;
        out[off + d] = (float)((t[i] - mean) * scale * (double)g[d] + (double)bta[d]);
    }
}

// ---------------- codebook squared norms (fp64)
__global__ __launch_bounds__(64) void k_cbn(const float* __restrict__ cb,
                                            double* __restrict__ cbn) {
    int row = blockIdx.x;
    int tid = threadIdx.x;
    const float* r = cb + (size_t)row * DMODEL;
    double s = 0.0;
    for (int d = tid; d < DMODEL; d += 64) { double v = (double)r[d]; s = fma(v, v, s); }
#pragma unroll
    for (int o = 32; o > 0; o >>= 1) s += __shfl_down(s, o, 64);
    if (tid == 0) cbn[row] = s;
}

// ---------------- split fp32 -> (bf16 hi, bf16 lo residual), RNE bit math
__device__ __forceinline__ unsigned short f2bf(float f) {
    unsigned u = __float_as_uint(f);
    unsigned r = (u + 0x7fffu + ((u >> 16) & 1u)) >> 16;
    return (unsigned short)r;
}
__device__ __forceinline__ float bf2f(unsigned short h) {
    return __uint_as_float(((unsigned)h) << 16);
}

__global__ __launch_bounds__(256) void k_split(const float* __restrict__ in,
                                               unsigned short* __restrict__ hi,
                                               unsigned short* __restrict__ lo,
                                               int n4) {
    int i = blockIdx.x * 256 + threadIdx.x;
    if (i >= n4) return;
    float4 v = ((const float4*)in)[i];
    float vv[4] = {v.x, v.y, v.z, v.w};
    unsigned short h[4], l[4];
#pragma unroll
    for (int j = 0; j < 4; j++) {
        h[j] = f2bf(vv[j]);
        l[j] = f2bf(vv[j] - bf2f(h[j]));
    }
    ((ushort4*)hi)[i] = make_ushort4(h[0], h[1], h[2], h[3]);
    ((ushort4*)lo)[i] = make_ushort4(l[0], l[1], l[2], l[3]);
}

// ---------------- VQ phase 1: split-bf16 MFMA GEMM, LDS-staged (m97-style).
__global__ __launch_bounds__(256) void k_vq1m(const unsigned short* __restrict__ xh,
                                              const unsigned short* __restrict__ xl,
                                              const unsigned short* __restrict__ ch,
                                              const unsigned short* __restrict__ cl,
                                              const double* __restrict__ cbn,
                                              float4* __restrict__ cand) {
    __shared__ __align__(16) unsigned char smem[65536];
    unsigned short* AhU = (unsigned short*)smem;           // [128][64]
    unsigned short* AlU = AhU + 8192;
    unsigned short* BhU = AlU + 8192;
    unsigned short* BlU = BhU + 8192;

    int tid = threadIdx.x;
    int lane = tid & 63, wave = tid >> 6;
    int lrow = lane & 15;
    int lkg = lane >> 4;
    int wr = wave >> 1, wc = wave & 1;
    int wrbase = wr * 64, wcbase = wc * 64;

    int wg = (blockIdx.x & 7) * (6272 / 8) + (blockIdx.x >> 3);
    int bx = wg / 98;
    int by = wg % 98;
    int r0 = by * 128, c0 = bx * 128;

    const int srow = tid >> 3;
    const int seg = tid & 7;
    const int sw = seg ^ (srow & 7);

    f32x4 acc[4][4];
#pragma unroll
    for (int m = 0; m < 4; m++)
#pragma unroll
        for (int n = 0; n < 4; n++) acc[m][n] = (f32x4){0.0f, 0.0f, 0.0f, 0.0f};

    for (int ks = 0; ks < 8; ks++) {
        int k0 = ks * 64;
#pragma unroll
        for (int rd = 0; rd < 4; rd++) {
            int row = rd * 32 + srow;
            size_t ga = (((size_t)(r0 + row)) << 9) + k0 + seg * 8;
            size_t gb = (((size_t)(c0 + row)) << 9) + k0 + seg * 8;
            int la = row * 64 + sw * 8;
            *(short8v*)(AhU + la) = *(const short8v*)(xh + ga);
            *(short8v*)(AlU + la) = *(const short8v*)(xl + ga);
            *(short8v*)(BhU + la) = *(const short8v*)(ch + gb);
            *(short8v*)(BlU + la) = *(const short8v*)(cl + gb);
        }
        __syncthreads();
#pragma unroll
        for (int ksub = 0; ksub < 2; ksub++) {
            int segsw = ((ksub * 4 + lkg) ^ (lrow & 7)) * 8;
            short8v afh[4], afl[4], bfh[4], bfl[4];
#pragma unroll
            for (int m = 0; m < 4; m++) {
                int off = (wrbase + m * 16 + lrow) * 64 + segsw;
                afh[m] = *(const short8v*)(AhU + off);
                afl[m] = *(const short8v*)(AlU + off);
            }
#pragma unroll
            for (int n = 0; n < 4; n++) {
                int off = (wcbase + n * 16 + lrow) * 64 + segsw;
                bfh[n] = *(const short8v*)(BhU + off);
                bfl[n] = *(const short8v*)(BlU + off);
            }
#pragma unroll
            for (int m = 0; m < 4; m++)
#pragma unroll
                for (int n = 0; n < 4; n++) {
                    acc[m][n] = __builtin_amdgcn_mfma_f32_16x16x32_bf16(afh[m], bfh[n], acc[m][n], 0, 0, 0);
                    acc[m][n] = __builtin_amdgcn_mfma_f32_16x16x32_bf16(afh[m], bfl[n], acc[m][n], 0, 0, 0);
                    acc[m][n] = __builtin_amdgcn_mfma_f32_16x16x32_bf16(afl[m], bfh[n], acc[m][n], 0, 0, 0);
                }
        }
        __syncthreads();
    }

    float cnv[4];
#pragma unroll
    for (int n = 0; n < 4; n++) cnv[n] = (float)cbn[c0 + wcbase + n * 16 + lrow];

    float* sD = (float*)smem;
    int* sI = (int*)(smem + 32768);
#pragma unroll
    for (int m = 0; m < 4; m++)
#pragma unroll
        for (int v = 0; v < 4; v++) {
            int row = wrbase + m * 16 + lkg * 4 + v;
            float d1 = 1e30f, d2 = 1e30f; int j1 = 0, j2 = 0;
#pragma unroll
            for (int n = 0; n < 4; n++) {
                int code = c0 + wcbase + n * 16 + lrow;
                float d = cnv[n] - 2.0f * acc[m][n][v];
                if (d < d1 || (d == d1 && code < j1)) { d2 = d1; j2 = j1; d1 = d; j1 = code; }
                else if (d < d2 || (d == d2 && code < j2)) { d2 = d; j2 = code; }
            }
            int slot = (wc * 16 + lrow) * 2;
            sD[row * 64 + slot] = d1; sD[row * 64 + slot + 1] = d2;
            sI[row * 64 + slot] = j1; sI[row * 64 + slot + 1] = j2;
        }
    __syncthreads();
    if (tid < 128) {
        float d1 = 1e30f, d2 = 1e30f; int j1 = 0, j2 = 0;
        for (int e = 0; e < 64; e++) {
            float d = sD[tid * 64 + e]; int ix = sI[tid * 64 + e];
            if (d < d1 || (d == d1 && ix < j1)) { d2 = d1; j2 = j1; d1 = d; j1 = ix; }
            else if (d < d2 || (d == d2 && ix < j2)) { d2 = d; j2 = ix; }
        }
        cand[(size_t)bx * NROWS + r0 + tid] =
            make_float4(d1, __int_as_float(j1), d2, __int_as_float(j2));
    }
}

// ---------------- VQ phase 2: merge 64 splits' top-2; flag near-ties
__global__ __launch_bounds__(256) void k_vq2(const float4* __restrict__ cand,
                                             int* __restrict__ idxbuf,
                                             int* __restrict__ flagbuf, int nrows) {
    int row = blockIdx.x * 256 + threadIdx.x;
    if (row >= nrows) return;
    float d1 = 1e30f, d2 = 1e30f; int j1 = 0, j2 = 0;
    for (int s = 0; s < NSPLIT; s++) {
        float4 c = cand[(size_t)s * nrows + row];
        float dd[2] = {c.x, c.z};
        int ii[2] = {__float_as_int(c.y), __float_as_int(c.w)};
#pragma unroll
        for (int e = 0; e < 2; e++) {
            float d = dd[e]; int ix = ii[e];
            if (d < d1 || (d == d1 && ix < j1)) { d2 = d1; j2 = j1; d1 = d; j1 = ix; }
            else if (d < d2 || (d == d2 && ix < j2)) { d2 = d; j2 = ix; }
        }
    }
    idxbuf[row] = j1;
    flagbuf[row] = (d2 - d1 < VEPS) ? 1 : 0;
}

// ---------------- VQ phase 3: exact fp64 rescan (4-way ILP) for flagged rows
__global__ __launch_bounds__(256) void k_vq3(const float* __restrict__ x,
                                             const float* __restrict__ cb,
                                             const double* __restrict__ cbn,
                                             const int* __restrict__ idxbuf,
                                             const int* __restrict__ flagbuf,
                                             float* __restrict__ outq,
                                             float* __restrict__ outi) {
    int row = blockIdx.x;
    int tid = threadIdx.x;
    int best = idxbuf[row];
    if (flagbuf[row]) {
        __shared__ __align__(16) float xs[DMODEL];
        __shared__ double sd[256];
        __shared__ int si[256];
        xs[tid] = x[(size_t)row * DMODEL + tid];
        xs[tid + 256] = x[(size_t)row * DMODEL + tid + 256];
        __syncthreads();
        double bd = 1e300; int bi = 0x7fffffff;
        const float4* xs4 = (const float4*)xs;
        for (int c = tid; c < KCB; c += 256) {
            const float4* cr4 = (const float4*)(cb + (size_t)c * DMODEL);
            double d0 = 0.0, d1 = 0.0, d2 = 0.0, d3 = 0.0;
#pragma unroll 8
            for (int q = 0; q < DMODEL / 4; q++) {
                float4 cv = cr4[q];
                float4 xv = xs4[q];
                d0 = fma((double)xv.x, (double)cv.x, d0);
                d1 = fma((double)xv.y, (double)cv.y, d1);
                d2 = fma((double)xv.z, (double)cv.z, d2);
                d3 = fma((double)xv.w, (double)cv.w, d3);
            }
            double dot = (d0 + d1) + (d2 + d3);
            double dist = cbn[c] - 2.0 * dot;
            if (dist < bd || (dist == bd && c < bi)) { bd = dist; bi = c; }
        }
        sd[tid] = bd; si[tid] = bi;
        __syncthreads();
        for (int off = 128; off > 0; off >>= 1) {
            if (tid < off) {
                if (sd[tid + off] < sd[tid] ||
                    (sd[tid + off] == sd[tid] && si[tid + off] < si[tid])) {
                    sd[tid] = sd[tid + off]; si[tid] = si[tid + off];
                }
            }
            __syncthreads();
        }
        best = si[0];
    }
    const float* crow = cb + (size_t)best * DMODEL;
    outq[(size_t)row * DMODEL + tid] = crow[tid];
    outq[(size_t)row * DMODEL + tid + 256] = crow[tid + 256];
    if (tid == 0) outi[row] = (float)best;
}

extern "C" void kernel_launch(void* const* d_in, const int* in_sizes, int n_in,
                              void* d_out, int out_size, void* d_ws, size_t ws_size,
                              hipStream_t stream) {
    const float* motion = (const float*)d_in[0];
    const float* conv_w = (const float*)d_in[1];
    const float* conv_b = (const float*)d_in[2];
    const float* wqkv   = (const float*)d_in[3];
    const float* bqkv   = (const float*)d_in[4];
    const float* wo     = (const float*)d_in[5];
    const float* bo     = (const float*)d_in[6];
    const float* ln1g   = (const float*)d_in[7];
    const float* ln1b   = (const float*)d_in[8];
    const float* ln2g   = (const float*)d_in[9];
    const float* ln2b   = (const float*)d_in[10];
    const float* w1     = (const float*)d_in[11];
    const float* b1     = (const float*)d_in[12];
    const float* w2     = (const float*)d_in[13];
    const float* b2     = (const float*)d_in[14];
    const float* cb     = (const float*)d_in[15];

    const size_t SZc = (size_t)25088 * DMODEL;
    float* wsf = (float*)d_ws;
    float*  S0  = wsf + 0 * SZc;
    float*  S1  = wsf + 1 * SZc;
    float*  S2  = wsf + 2 * SZc;
    float*  S3  = wsf + 3 * SZc;
    float*  Wc  = wsf + 4 * SZc;
    char* p = (char*)(Wc + 2 * 3 * DMODEL * DMODEL);
    double* cbn   = (double*)p;            p += KCB * 8;
    int*   idxbuf = (int*)p;               p += NROWS * 4;
    int*   flagbuf= (int*)p;

    k_cbn<<<dim3(KCB), dim3(64), 0, stream>>>(cb, cbn);
    k_wconv<<<dim3(3072), dim3(256), 0, stream>>>(conv_w, Wc);
    k_wconv<<<dim3(3072), dim3(256), 0, stream>>>(conv_w + (size_t)3 * DMODEL * DMODEL,
                                                  Wc + (size_t)3 * DMODEL * DMODEL);

    const float* xin = motion;
    int Tin = 196;
    for (int l = 0; l < 2; l++) {
        int Tout = Tin / 2;            // 98, then 49
        int M = BBATCH * Tout;         // 25088, then 12544
        const float* wq = wqkv + (size_t)l * DMODEL * 3 * DMODEL;
        const float* bq = bqkv + (size_t)l * 3 * DMODEL;
        const float* WcL = Wc + (size_t)l * 3 * DMODEL * DMODEL;

        // conv (fused gather + exact fp64 GELU epilogue)
        k_gemm32<1, 1><<<dim3(4, M / 128), dim3(256), 0, stream>>>(
            xin, DMODEL, WcL, DMODEL, conv_b + l * DMODEL, S0, DMODEL,
            3 * DMODEL, Tin, Tout);
        // qkv
        float* qkvdst[3] = {S1, S2, S3};
        for (int s = 0; s < 3; s++) {
            k_gemm32<0, 0><<<dim3(4, M / 128), dim3(256), 0, stream>>>(
                S0, DMODEL, wq + s * DMODEL, 3 * DMODEL, bq + s * DMODEL,
                qkvdst[s], DMODEL, DMODEL, 1, 1);
        }
        k_attn<<<dim3(NHEAD, BBATCH), dim3(256), 0, stream>>>(S1, S2, S3, S1, Tout);
        // wo
        k_gemm32<0, 0><<<dim3(4, M / 128), dim3(256), 0, stream>>>(
            S1, DMODEL, wo + (size_t)l * DMODEL * DMODEL, DMODEL, bo + l * DMODEL,
            S2, DMODEL, DMODEL, 1, 1);
        k_ln<<<dim3(M), dim3(128), 0, stream>>>(S0, S2, ln1g + l * DMODEL, ln1b + l * DMODEL, S3);
        // ffn
        k_gemm32<2, 0><<<dim3(8, M / 128), dim3(256), 0, stream>>>(
            S3, DMODEL, w1 + (size_t)l * DMODEL * DFFN, DFFN, b1 + l * DFFN,
            S1, DFFN, DMODEL, 1, 1);
        k_gemm32<0, 0><<<dim3(4, M / 128), dim3(256), 0, stream>>>(
            S1, DFFN, w2 + (size_t)l * DFFN * DMODEL, DMODEL, b2 + l * DMODEL,
            S0, DMODEL, DFFN, 1, 1);
        k_ln<<<dim3(M), dim3(128), 0, stream>>>(S3, S0, ln2g + l * DMODEL, ln2b + l * DMODEL, S1);

        xin = S1;
        Tin = Tout;
    }

    // ---- VQ: split x (S1) and codebook to bf16 hi/lo in freed scratch (S2, S3).
    // cand (64 splits x NROWS float4 = 12.85 MB) lives in freed S0.
    unsigned short* xh = (unsigned short*)S2;
    unsigned short* xl = xh + (size_t)NROWS * DMODEL;
    unsigned short* chb = (unsigned short*)S3;
    unsigned short* clb = chb + (size_t)KCB * DMODEL;
    float4* cand = (float4*)S0;
    k_split<<<dim3(NROWS * DMODEL / 4 / 256), dim3(256), 0, stream>>>(S1, xh, xl,
                                                                      NROWS * DMODEL / 4);
    k_split<<<dim3(KCB * DMODEL / 4 / 256), dim3(256), 0, stream>>>(cb, chb, clb,
                                                                    KCB * DMODEL / 4);

    float* outq = (float*)d_out;
    float* outi = outq + (size_t)NROWS * DMODEL;
    k_vq1m<<<dim3(98 * NSPLIT), dim3(256), 0, stream>>>(xh, xl, chb, clb, cbn, cand);
    k_vq2<<<dim3(49), dim3(256), 0, stream>>>(cand, idxbuf, flagbuf, NROWS);
    k_vq3<<<dim3(NROWS), dim3(256), 0, stream>>>(S1, cb, cbn, idxbuf, flagbuf, outq, outi);
}

// Round 6
// 3819.254 us; speedup vs baseline: 1.4457x; 1.4457x over previous
//
#include <hip/hip_runtime.h>
#include <hip/hip_bf16.h>
#include <math.h>

#define BBATCH 256
#define DMODEL 512
#define NHEAD 4
#define DHEAD 128
#define DFFN 1024
#define KCB 8192
#define VEPS 0.02f
#define NROWS 12544
#define NSPLIT 64   // 8192 / 128 code tiles

typedef __attribute__((ext_vector_type(8))) short short8v;   // 8 bf16 in 4 VGPRs
typedef __attribute__((ext_vector_type(4))) float f32x4;

// ---------------- exact 3-way truncation split: x == hi + mid + lo (24 mantissa bits)
__device__ __forceinline__ void tsplit3(float x, unsigned short& h,
                                        unsigned short& m, unsigned short& l) {
    unsigned u = __float_as_uint(x);
    float hf = __uint_as_float(u & 0xffff0000u);
    float r = x - hf;                       // exact
    unsigned ru = __float_as_uint(r);
    float mf = __uint_as_float(ru & 0xffff0000u);
    float r2 = r - mf;                      // exact
    h = (unsigned short)(u >> 16);
    m = (unsigned short)(ru >> 16);
    l = (unsigned short)(__float_as_uint(r2) >> 16);
}

// ---------------- weight transpose + 3-way split: W[K][N] (ldw) -> [N][K] bf16 h/m/l
__global__ __launch_bounds__(256) void k_wsplit3T(const float* __restrict__ W, int ldw,
                                                  int K, int total,
                                                  unsigned short* __restrict__ th,
                                                  unsigned short* __restrict__ tm,
                                                  unsigned short* __restrict__ tl) {
    int idx = blockIdx.x * 256 + threadIdx.x;
    if (idx >= total) return;
    int n = idx / K, k = idx - n * K;
    unsigned short h, m, l;
    tsplit3(W[(size_t)k * ldw + n], h, m, l);
    th[idx] = h; tm[idx] = m; tl[idx] = l;
}

// ---------------- conv weight: cw[dout][di][kk] -> [dout][k=kk*512+di] bf16 h/m/l
__global__ __launch_bounds__(256) void k_wsplit3_conv(const float* __restrict__ cw,
                                                      unsigned short* __restrict__ th,
                                                      unsigned short* __restrict__ tm,
                                                      unsigned short* __restrict__ tl) {
    int idx = blockIdx.x * 256 + threadIdx.x;
    if (idx >= DMODEL * 3 * DMODEL) return;
    int dout = idx / 1536, k = idx - dout * 1536;
    int kk = k >> 9, di = k & 511;
    unsigned short h, m, l;
    tsplit3(cw[(size_t)dout * 1536 + di * 3 + kk], h, m, l);
    th[idx] = h; tm[idx] = m; tl[idx] = l;
}

// ---------------- 9-term split-bf16 MFMA GEMM: exact fp32-grade numerics.
// C[M][N] = act(A[M][K] @ Bt^T + bias); Bt = [N][K] pre-split h/m/l; A split in-staging.
// 128x128 tile, BK=32, 4 waves 2x2 (64x64, 4x4 f32x4 accs). LDS 6x8KB, swizzle
// seg^((row>>1)&3) on write+read (2-way conflicts = free). ACT: 0 none,1 GELU,2 relu.
template <int ACT, int CONV>
__global__ __launch_bounds__(256) void k_gemm6(const float* __restrict__ A, int lda,
                                               const unsigned short* __restrict__ B3h,
                                               const unsigned short* __restrict__ B3m,
                                               const unsigned short* __restrict__ B3l,
                                               const float* __restrict__ bias,
                                               float* __restrict__ C, int ldc,
                                               int K, int Tin, int Tout) {
    __shared__ __align__(16) unsigned short Ah[4096], Am[4096], Al[4096];
    __shared__ __align__(16) unsigned short Bh[4096], Bm[4096], Bl[4096];

    int tid = threadIdx.x;
    int lane = tid & 63, wave = tid >> 6;
    int lrow = lane & 15, lkg = lane >> 4;
    int wr = wave >> 1, wc = wave & 1;
    int wrbase = wr * 64, wcbase = wc * 64;
    int n0 = blockIdx.x * 128, m0 = blockIdx.y * 128;

    int sr[2], ss[2]; size_t abase[2], bbase[2]; int attv[2];
#pragma unroll
    for (int rd = 0; rd < 2; rd++) {
        int slot = tid + rd * 256;
        int row = slot >> 2, seg = slot & 3;
        sr[rd] = row; ss[rd] = seg;
        bbase[rd] = (size_t)(n0 + row) * K + seg * 8;
        int m = m0 + row;
        if (CONV) {
            int b = m / Tout, tt = m - b * Tout;
            abase[rd] = (size_t)b * Tin * DMODEL;
            attv[rd] = 2 * tt - 2;
        } else {
            abase[rd] = (size_t)m * lda + seg * 8;
            attv[rd] = 0;
        }
    }

    f32x4 acc[4][4];
#pragma unroll
    for (int mi = 0; mi < 4; mi++)
#pragma unroll
        for (int ni = 0; ni < 4; ni++) acc[mi][ni] = (f32x4){0.0f, 0.0f, 0.0f, 0.0f};

    for (int k0 = 0; k0 < K; k0 += 32) {
#pragma unroll
        for (int rd = 0; rd < 2; rd++) {
            int row = sr[rd], seg = ss[rd];
            int la = row * 32 + ((seg ^ ((row >> 1) & 3)) << 3);
            *(short8v*)(Bh + la) = *(const short8v*)(B3h + bbase[rd] + k0);
            *(short8v*)(Bm + la) = *(const short8v*)(B3m + bbase[rd] + k0);
            *(short8v*)(Bl + la) = *(const short8v*)(B3l + bbase[rd] + k0);
            const float* ap;
            if (CONV) {
                int f = attv[rd] + (k0 >> 9);
                if (f < 0) f = 0;
                ap = A + abase[rd] + (size_t)f * DMODEL + (k0 & 511) + seg * 8;
            } else {
                ap = A + abase[rd] + k0;
            }
            float4 v0 = *(const float4*)ap;
            float4 v1 = *(const float4*)(ap + 4);
            float vv[8] = {v0.x, v0.y, v0.z, v0.w, v1.x, v1.y, v1.z, v1.w};
            short8v hv, mv, lv;
#pragma unroll
            for (int j = 0; j < 8; j++) {
                unsigned short h, m, l;
                tsplit3(vv[j], h, m, l);
                hv[j] = (short)h; mv[j] = (short)m; lv[j] = (short)l;
            }
            *(short8v*)(Ah + la) = hv;
            *(short8v*)(Am + la) = mv;
            *(short8v*)(Al + la) = lv;
        }
        __syncthreads();

        short8v afh[4], afm[4], afl[4];
#pragma unroll
        for (int mi = 0; mi < 4; mi++) {
            int rowa = wrbase + mi * 16 + lrow;
            int off = rowa * 32 + ((lkg ^ ((rowa >> 1) & 3)) << 3);
            afh[mi] = *(const short8v*)(Ah + off);
            afm[mi] = *(const short8v*)(Am + off);
            afl[mi] = *(const short8v*)(Al + off);
        }
#pragma unroll
        for (int ni = 0; ni < 4; ni++) {
            int rowb = wcbase + ni * 16 + lrow;
            int off = rowb * 32 + ((lkg ^ ((rowb >> 1) & 3)) << 3);
            short8v bfh = *(const short8v*)(Bh + off);
            short8v bfm = *(const short8v*)(Bm + off);
            short8v bfl = *(const short8v*)(Bl + off);
#pragma unroll
            for (int mi = 0; mi < 4; mi++) {
                acc[mi][ni] = __builtin_amdgcn_mfma_f32_16x16x32_bf16(afh[mi], bfh, acc[mi][ni], 0, 0, 0);
                acc[mi][ni] = __builtin_amdgcn_mfma_f32_16x16x32_bf16(afh[mi], bfm, acc[mi][ni], 0, 0, 0);
                acc[mi][ni] = __builtin_amdgcn_mfma_f32_16x16x32_bf16(afm[mi], bfh, acc[mi][ni], 0, 0, 0);
                acc[mi][ni] = __builtin_amdgcn_mfma_f32_16x16x32_bf16(afh[mi], bfl, acc[mi][ni], 0, 0, 0);
                acc[mi][ni] = __builtin_amdgcn_mfma_f32_16x16x32_bf16(afl[mi], bfh, acc[mi][ni], 0, 0, 0);
                acc[mi][ni] = __builtin_amdgcn_mfma_f32_16x16x32_bf16(afm[mi], bfm, acc[mi][ni], 0, 0, 0);
                acc[mi][ni] = __builtin_amdgcn_mfma_f32_16x16x32_bf16(afm[mi], bfl, acc[mi][ni], 0, 0, 0);
                acc[mi][ni] = __builtin_amdgcn_mfma_f32_16x16x32_bf16(afl[mi], bfm, acc[mi][ni], 0, 0, 0);
                acc[mi][ni] = __builtin_amdgcn_mfma_f32_16x16x32_bf16(afl[mi], bfl, acc[mi][ni], 0, 0, 0);
            }
        }
        __syncthreads();
    }

    float bv[4];
#pragma unroll
    for (int ni = 0; ni < 4; ni++) bv[ni] = bias[n0 + wcbase + ni * 16 + lrow];
#pragma unroll
    for (int mi = 0; mi < 4; mi++)
#pragma unroll
        for (int ni = 0; ni < 4; ni++)
#pragma unroll
            for (int v = 0; v < 4; v++) {
                int row = m0 + wrbase + mi * 16 + lkg * 4 + v;
                int col = n0 + wcbase + ni * 16 + lrow;
                float x;
                if (ACT == 1) {
                    double dv = (double)acc[mi][ni][v] + (double)bv[ni];
                    dv = 0.5 * dv * (1.0 + erf(dv * 0.7071067811865476));
                    x = (float)dv;
                } else {
                    x = acc[mi][ni][v] + bv[ni];
                    if (ACT == 2) x = x > 0.0f ? x : 0.0f;
                }
                C[(size_t)row * ldc + col] = x;
            }
}

// ---------------- broadcast helper: uniform lane read
__device__ __forceinline__ float lanebc(float x, int l) {
    return __int_as_float(__builtin_amdgcn_readlane(__float_as_int(x), l));
}

// ---------------- attention: one block per (h, b); 4 waves, rows i%4==wave.
__global__ __launch_bounds__(256) void k_attn(const float* q,
                                              const float* __restrict__ k,
                                              const float* __restrict__ v,
                                              float* out, int T) {
    __shared__ float Ks[98][129];
    int h = blockIdx.x, b = blockIdx.y;
    int tid = threadIdx.x;
    int lane = tid & 63;
    int wave = tid >> 6;
    size_t base = ((size_t)b * T) * DMODEL + (size_t)h * DHEAD;

    for (int idx = tid; idx < T * DHEAD; idx += 256) {
        int j = idx >> 7, d = idx & 127;
        Ks[j][d] = k[base + (size_t)j * DMODEL + d];
    }
    __syncthreads();

    const float SCALE = 0.08838834764831845f;
    for (int i = wave; i < T; i += 4) {
        float qa = q[base + (size_t)i * DMODEL + lane];
        float qb = q[base + (size_t)i * DMODEL + lane + 64];

        int j1 = lane;
        int j2 = lane + 64;
        int j2c = j2 < T ? j2 : 0;
        bool a0 = (j1 <= i);
        bool a1 = (j2 <= i);

        float s0 = 0.0f, s1 = 0.0f;
#pragma unroll 8
        for (int d = 0; d < 64; d++) {
            float qd = lanebc(qa, d);
            s0 = fmaf(qd, Ks[j1][d], s0);
            s1 = fmaf(qd, Ks[j2c][d], s1);
        }
#pragma unroll 8
        for (int d = 0; d < 64; d++) {
            float qd = lanebc(qb, d);
            s0 = fmaf(qd, Ks[j1][64 + d], s0);
            s1 = fmaf(qd, Ks[j2c][64 + d], s1);
        }
        float s0v = a0 ? s0 * SCALE : -1e30f;
        float s1v = a1 ? s1 * SCALE : -1e30f;

        float m = fmaxf(s0v, s1v);
#pragma unroll
        for (int off = 32; off > 0; off >>= 1) m = fmaxf(m, __shfl_xor(m, off, 64));

        float p0 = a0 ? expf(s0v - m) : 0.0f;
        float p1 = a1 ? expf(s1v - m) : 0.0f;

        float sum = p0 + p1;
#pragma unroll
        for (int off = 32; off > 0; off >>= 1) sum += __shfl_xor(sum, off, 64);
        float inv = 1.0f / sum;

        float o0 = 0.0f, o1 = 0.0f;
        int jmax0 = i < 63 ? i : 63;
        for (int j = 0; j <= jmax0; j++) {
            float pj = lanebc(p0, j);
            const float* vr = v + base + (size_t)j * DMODEL;
            o0 = fmaf(pj, vr[lane], o0);
            o1 = fmaf(pj, vr[lane + 64], o1);
        }
        for (int j = 64; j <= i; j++) {
            float pj = lanebc(p1, j - 64);
            const float* vr = v + base + (size_t)j * DMODEL;
            o0 = fmaf(pj, vr[lane], o0);
            o1 = fmaf(pj, vr[lane + 64], o1);
        }
        out[base + (size_t)i * DMODEL + lane] = o0 * inv;
        out[base + (size_t)i * DMODEL + lane + 64] = o1 * inv;
    }
}

// ---------------- fused residual-add + LayerNorm
__global__ __launch_bounds__(128) void k_ln(const float* __restrict__ resid,
                                            const float* __restrict__ y,
                                            const float* __restrict__ g,
                                            const float* __restrict__ bta,
                                            float* __restrict__ out) {
    int row = blockIdx.x;
    int tid = threadIdx.x;
    size_t off = (size_t)row * DMODEL;
    double t[4];
#pragma unroll
    for (int i = 0; i < 4; i++) {
        int d = tid + i * 128;
        t[i] = (double)resid[off + d] + (double)y[off + d];
    }
    __shared__ double rd[2];
    double s = t[0] + t[1] + t[2] + t[3];
#pragma unroll
    for (int o = 32; o > 0; o >>= 1) s += __shfl_down(s, o, 64);
    if ((tid & 63) == 0) rd[tid >> 6] = s;
    __syncthreads();
    double mean = (rd[0] + rd[1]) * (1.0 / 512.0);
    double vs = 0.0;
#pragma unroll
    for (int i = 0; i < 4; i++) { double dl = t[i] - mean; vs += dl * dl; }
    __syncthreads();
#pragma unroll
    for (int o = 32; o > 0; o >>= 1) vs += __shfl_down(vs, o, 64);
    if ((tid & 63) == 0) rd[tid >> 6] = vs;
    __syncthreads();
    double var = (rd[0] + rd[1]) * (1.0 / 512.0);
    double scale = 1.0 / sqrt(var + 1e-5);
#pragma unroll
    for (int i = 0; i < 4; i++) {
        int d = tid + i * 128;
        out[off + d] = (float)((t[i] - mean) * scale * (double)g[d] + (double)bta[d]);
    }
}

// ---------------- codebook squared norms (fp64)
__global__ __launch_bounds__(64) void k_cbn(const float* __restrict__ cb,
                                            double* __restrict__ cbn) {
    int row = blockIdx.x;
    int tid = threadIdx.x;
    const float* r = cb + (size_t)row * DMODEL;
    double s = 0.0;
    for (int d = tid; d < DMODEL; d += 64) { double v = (double)r[d]; s = fma(v, v, s); }
#pragma unroll
    for (int o = 32; o > 0; o >>= 1) s += __shfl_down(s, o, 64);
    if (tid == 0) cbn[row] = s;
}

// ---------------- split fp32 -> (bf16 hi, bf16 lo residual), RNE (VQ path, verified)
__device__ __forceinline__ unsigned short f2bf(float f) {
    unsigned u = __float_as_uint(f);
    unsigned r = (u + 0x7fffu + ((u >> 16) & 1u)) >> 16;
    return (unsigned short)r;
}
__device__ __forceinline__ float bf2f(unsigned short h) {
    return __uint_as_float(((unsigned)h) << 16);
}

__global__ __launch_bounds__(256) void k_split(const float* __restrict__ in,
                                               unsigned short* __restrict__ hi,
                                               unsigned short* __restrict__ lo,
                                               int n4) {
    int i = blockIdx.x * 256 + threadIdx.x;
    if (i >= n4) return;
    float4 v = ((const float4*)in)[i];
    float vv[4] = {v.x, v.y, v.z, v.w};
    unsigned short h[4], l[4];
#pragma unroll
    for (int j = 0; j < 4; j++) {
        h[j] = f2bf(vv[j]);
        l[j] = f2bf(vv[j] - bf2f(h[j]));
    }
    ((ushort4*)hi)[i] = make_ushort4(h[0], h[1], h[2], h[3]);
    ((ushort4*)lo)[i] = make_ushort4(l[0], l[1], l[2], l[3]);
}

// ---------------- codebook transpose: cbT[d][c] = cb[c][d] (LDS-tiled, coalesced)
__global__ __launch_bounds__(256) void k_cbT(const float* __restrict__ cb,
                                             float* __restrict__ cbT) {
    __shared__ float t[64][65];
    int c0 = blockIdx.x * 64, d0 = blockIdx.y * 64;
    int tid = threadIdx.x;
#pragma unroll
    for (int i = 0; i < 16; i++) {
        int e = tid + i * 256;
        t[e >> 6][e & 63] = cb[(size_t)(c0 + (e >> 6)) * DMODEL + d0 + (e & 63)];
    }
    __syncthreads();
#pragma unroll
    for (int i = 0; i < 16; i++) {
        int e = tid + i * 256;
        int d = e >> 6, c = e & 63;
        cbT[(size_t)(d0 + d) * KCB + c0 + c] = t[c][d];
    }
}

// ---------------- VQ phase 1: split-bf16 MFMA GEMM, LDS-staged (verified r3/r5).
__global__ __launch_bounds__(256) void k_vq1m(const unsigned short* __restrict__ xh,
                                              const unsigned short* __restrict__ xl,
                                              const unsigned short* __restrict__ ch,
                                              const unsigned short* __restrict__ cl,
                                              const double* __restrict__ cbn,
                                              float4* __restrict__ cand) {
    __shared__ __align__(16) unsigned char smem[65536];
    unsigned short* AhU = (unsigned short*)smem;           // [128][64]
    unsigned short* AlU = AhU + 8192;
    unsigned short* BhU = AlU + 8192;
    unsigned short* BlU = BhU + 8192;

    int tid = threadIdx.x;
    int lane = tid & 63, wave = tid >> 6;
    int lrow = lane & 15;
    int lkg = lane >> 4;
    int wr = wave >> 1, wc = wave & 1;
    int wrbase = wr * 64, wcbase = wc * 64;

    int wg = (blockIdx.x & 7) * (6272 / 8) + (blockIdx.x >> 3);
    int bx = wg / 98;
    int by = wg % 98;
    int r0 = by * 128, c0 = bx * 128;

    const int srow = tid >> 3;
    const int seg = tid & 7;
    const int sw = seg ^ (srow & 7);

    f32x4 acc[4][4];
#pragma unroll
    for (int m = 0; m < 4; m++)
#pragma unroll
        for (int n = 0; n < 4; n++) acc[m][n] = (f32x4){0.0f, 0.0f, 0.0f, 0.0f};

    for (int ks = 0; ks < 8; ks++) {
        int k0 = ks * 64;
#pragma unroll
        for (int rd = 0; rd < 4; rd++) {
            int row = rd * 32 + srow;
            size_t ga = (((size_t)(r0 + row)) << 9) + k0 + seg * 8;
            size_t gb = (((size_t)(c0 + row)) << 9) + k0 + seg * 8;
            int la = row * 64 + sw * 8;
            *(short8v*)(AhU + la) = *(const short8v*)(xh + ga);
            *(short8v*)(AlU + la) = *(const short8v*)(xl + ga);
            *(short8v*)(BhU + la) = *(const short8v*)(ch + gb);
            *(short8v*)(BlU + la) = *(const short8v*)(cl + gb);
        }
        __syncthreads();
#pragma unroll
        for (int ksub = 0; ksub < 2; ksub++) {
            int segsw = ((ksub * 4 + lkg) ^ (lrow & 7)) * 8;
            short8v afh[4], afl[4], bfh[4], bfl[4];
#pragma unroll
            for (int m = 0; m < 4; m++) {
                int off = (wrbase + m * 16 + lrow) * 64 + segsw;
                afh[m] = *(const short8v*)(AhU + off);
                afl[m] = *(const short8v*)(AlU + off);
            }
#pragma unroll
            for (int n = 0; n < 4; n++) {
                int off = (wcbase + n * 16 + lrow) * 64 + segsw;
                bfh[n] = *(const short8v*)(BhU + off);
                bfl[n] = *(const short8v*)(BlU + off);
            }
#pragma unroll
            for (int m = 0; m < 4; m++)
#pragma unroll
                for (int n = 0; n < 4; n++) {
                    acc[m][n] = __builtin_amdgcn_mfma_f32_16x16x32_bf16(afh[m], bfh[n], acc[m][n], 0, 0, 0);
                    acc[m][n] = __builtin_amdgcn_mfma_f32_16x16x32_bf16(afh[m], bfl[n], acc[m][n], 0, 0, 0);
                    acc[m][n] = __builtin_amdgcn_mfma_f32_16x16x32_bf16(afl[m], bfh[n], acc[m][n], 0, 0, 0);
                }
        }
        __syncthreads();
    }

    float cnv[4];
#pragma unroll
    for (int n = 0; n < 4; n++) cnv[n] = (float)cbn[c0 + wcbase + n * 16 + lrow];

    float* sD = (float*)smem;
    int* sI = (int*)(smem + 32768);
#pragma unroll
    for (int m = 0; m < 4; m++)
#pragma unroll
        for (int v = 0; v < 4; v++) {
            int row = wrbase + m * 16 + lkg * 4 + v;
            float d1 = 1e30f, d2 = 1e30f; int j1 = 0, j2 = 0;
#pragma unroll
            for (int n = 0; n < 4; n++) {
                int code = c0 + wcbase + n * 16 + lrow;
                float d = cnv[n] - 2.0f * acc[m][n][v];
                if (d < d1 || (d == d1 && code < j1)) { d2 = d1; j2 = j1; d1 = d; j1 = code; }
                else if (d < d2 || (d == d2 && code < j2)) { d2 = d; j2 = code; }
            }
            int slot = (wc * 16 + lrow) * 2;
            sD[row * 64 + slot] = d1; sD[row * 64 + slot + 1] = d2;
            sI[row * 64 + slot] = j1; sI[row * 64 + slot + 1] = j2;
        }
    __syncthreads();
    if (tid < 128) {
        float d1 = 1e30f, d2 = 1e30f; int j1 = 0, j2 = 0;
        for (int e = 0; e < 64; e++) {
            float d = sD[tid * 64 + e]; int ix = sI[tid * 64 + e];
            if (d < d1 || (d == d1 && ix < j1)) { d2 = d1; j2 = j1; d1 = d; j1 = ix; }
            else if (d < d2 || (d == d2 && ix < j2)) { d2 = d; j2 = ix; }
        }
        cand[(size_t)bx * NROWS + r0 + tid] =
            make_float4(d1, __int_as_float(j1), d2, __int_as_float(j2));
    }
}

// ---------------- VQ phase 2: merge 64 splits' top-2; flag near-ties
__global__ __launch_bounds__(256) void k_vq2(const float4* __restrict__ cand,
                                             int* __restrict__ idxbuf,
                                             int* __restrict__ flagbuf, int nrows) {
    int row = blockIdx.x * 256 + threadIdx.x;
    if (row >= nrows) return;
    float d1 = 1e30f, d2 = 1e30f; int j1 = 0, j2 = 0;
    for (int s = 0; s < NSPLIT; s++) {
        float4 c = cand[(size_t)s * nrows + row];
        float dd[2] = {c.x, c.z};
        int ii[2] = {__float_as_int(c.y), __float_as_int(c.w)};
#pragma unroll
        for (int e = 0; e < 2; e++) {
            float d = dd[e]; int ix = ii[e];
            if (d < d1 || (d == d1 && ix < j1)) { d2 = d1; j2 = j1; d1 = d; j1 = ix; }
            else if (d < d2 || (d == d2 && ix < j2)) { d2 = d; j2 = ix; }
        }
    }
    idxbuf[row] = j1;
    flagbuf[row] = (d2 - d1 < VEPS) ? 1 : 0;
}

// ---------------- VQ phase 3: exact fp64 rescan via TRANSPOSED codebook (coalesced:
// lane-consecutive codes), fp64-VALU-bound. Flagged rows only; then write outputs.
__global__ __launch_bounds__(256) void k_vq3(const float* __restrict__ x,
                                             const float* __restrict__ cb,
                                             const float* __restrict__ cbT,
                                             const double* __restrict__ cbn,
                                             const int* __restrict__ idxbuf,
                                             const int* __restrict__ flagbuf,
                                             float* __restrict__ outq,
                                             float* __restrict__ outi) {
    int row = blockIdx.x;
    int tid = threadIdx.x;
    int best = idxbuf[row];
    if (flagbuf[row]) {
        __shared__ __align__(16) float xs[DMODEL];
        __shared__ double sd[256];
        __shared__ int si[256];
        xs[tid] = x[(size_t)row * DMODEL + tid];
        xs[tid + 256] = x[(size_t)row * DMODEL + tid + 256];
        __syncthreads();
        double bd = 1e300; int bi = 0x7fffffff;
        const float4* xs4 = (const float4*)xs;
        for (int c0 = 0; c0 < KCB; c0 += 256) {
            int c = c0 + tid;
            double a0 = 0.0, a1 = 0.0, a2 = 0.0, a3 = 0.0;
#pragma unroll 8
            for (int q = 0; q < DMODEL / 4; q++) {
                float4 xv = xs4[q];
                const float* cp = cbT + (size_t)(q * 4) * KCB + c;
                a0 = fma((double)xv.x, (double)cp[0], a0);
                a1 = fma((double)xv.y, (double)cp[KCB], a1);
                a2 = fma((double)xv.z, (double)cp[2 * KCB], a2);
                a3 = fma((double)xv.w, (double)cp[3 * KCB], a3);
            }
            double dist = cbn[c] - 2.0 * ((a0 + a1) + (a2 + a3));
            if (dist < bd || (dist == bd && c < bi)) { bd = dist; bi = c; }
        }
        sd[tid] = bd; si[tid] = bi;
        __syncthreads();
        for (int off = 128; off > 0; off >>= 1) {
            if (tid < off) {
                if (sd[tid + off] < sd[tid] ||
                    (sd[tid + off] == sd[tid] && si[tid + off] < si[tid])) {
                    sd[tid] = sd[tid + off]; si[tid] = si[tid + off];
                }
            }
            __syncthreads();
        }
        best = si[0];
    }
    const float* crow = cb + (size_t)best * DMODEL;
    outq[(size_t)row * DMODEL + tid] = crow[tid];
    outq[(size_t)row * DMODEL + tid + 256] = crow[tid + 256];
    if (tid == 0) outi[row] = (float)best;
}

extern "C" void kernel_launch(void* const* d_in, const int* in_sizes, int n_in,
                              void* d_out, int out_size, void* d_ws, size_t ws_size,
                              hipStream_t stream) {
    const float* motion = (const float*)d_in[0];
    const float* conv_w = (const float*)d_in[1];
    const float* conv_b = (const float*)d_in[2];
    const float* wqkv   = (const float*)d_in[3];
    const float* bqkv   = (const float*)d_in[4];
    const float* wo     = (const float*)d_in[5];
    const float* bo     = (const float*)d_in[6];
    const float* ln1g   = (const float*)d_in[7];
    const float* ln1b   = (const float*)d_in[8];
    const float* ln2g   = (const float*)d_in[9];
    const float* ln2b   = (const float*)d_in[10];
    const float* w1     = (const float*)d_in[11];
    const float* b1     = (const float*)d_in[12];
    const float* w2     = (const float*)d_in[13];
    const float* b2     = (const float*)d_in[14];
    const float* cb     = (const float*)d_in[15];

    const size_t SZc = (size_t)25088 * DMODEL;
    float* wsf = (float*)d_ws;
    float*  S0  = wsf + 0 * SZc;
    float*  S1  = wsf + 1 * SZc;
    float*  S2  = wsf + 2 * SZc;
    float*  S3  = wsf + 3 * SZc;
    char* p = (char*)(wsf + 4 * SZc);
    unsigned short* wh = (unsigned short*)p;   p += (size_t)786432 * 2;
    unsigned short* wm = (unsigned short*)p;   p += (size_t)786432 * 2;
    unsigned short* wl = (unsigned short*)p;   p += (size_t)786432 * 2;
    double* cbn   = (double*)p;                p += KCB * 8;
    int*   idxbuf = (int*)p;                   p += NROWS * 4;
    int*   flagbuf= (int*)p;

    k_cbn<<<dim3(KCB), dim3(64), 0, stream>>>(cb, cbn);

    const float* xin = motion;
    int Tin = 196;
    for (int l = 0; l < 2; l++) {
        int Tout = Tin / 2;            // 98, then 49
        int M = BBATCH * Tout;         // 25088, then 12544
        const float* wq = wqkv + (size_t)l * DMODEL * 3 * DMODEL;
        const float* bq = bqkv + (size_t)l * 3 * DMODEL;

        // conv (fused gather + exact fp64 GELU epilogue)
        k_wsplit3_conv<<<dim3(3072), dim3(256), 0, stream>>>(
            conv_w + (size_t)l * DMODEL * DMODEL * 3, wh, wm, wl);
        k_gemm6<1, 1><<<dim3(4, M / 128), dim3(256), 0, stream>>>(
            xin, DMODEL, wh, wm, wl, conv_b + l * DMODEL, S0, DMODEL,
            3 * DMODEL, Tin, Tout);
        // qkv
        float* qkvdst[3] = {S1, S2, S3};
        for (int s = 0; s < 3; s++) {
            k_wsplit3T<<<dim3(1024), dim3(256), 0, stream>>>(
                wq + s * DMODEL, 3 * DMODEL, DMODEL, DMODEL * DMODEL, wh, wm, wl);
            k_gemm6<0, 0><<<dim3(4, M / 128), dim3(256), 0, stream>>>(
                S0, DMODEL, wh, wm, wl, bq + s * DMODEL, qkvdst[s], DMODEL,
                DMODEL, 1, 1);
        }
        k_attn<<<dim3(NHEAD, BBATCH), dim3(256), 0, stream>>>(S1, S2, S3, S1, Tout);
        // wo
        k_wsplit3T<<<dim3(1024), dim3(256), 0, stream>>>(
            wo + (size_t)l * DMODEL * DMODEL, DMODEL, DMODEL, DMODEL * DMODEL, wh, wm, wl);
        k_gemm6<0, 0><<<dim3(4, M / 128), dim3(256), 0, stream>>>(
            S1, DMODEL, wh, wm, wl, bo + l * DMODEL, S2, DMODEL, DMODEL, 1, 1);
        k_ln<<<dim3(M), dim3(128), 0, stream>>>(S0, S2, ln1g + l * DMODEL, ln1b + l * DMODEL, S3);
        // ffn
        k_wsplit3T<<<dim3(2048), dim3(256), 0, stream>>>(
            w1 + (size_t)l * DMODEL * DFFN, DFFN, DMODEL, DMODEL * DFFN, wh, wm, wl);
        k_gemm6<2, 0><<<dim3(8, M / 128), dim3(256), 0, stream>>>(
            S3, DMODEL, wh, wm, wl, b1 + l * DFFN, S1, DFFN, DMODEL, 1, 1);
        k_wsplit3T<<<dim3(2048), dim3(256), 0, stream>>>(
            w2 + (size_t)l * DFFN * DMODEL, DMODEL, DFFN, DMODEL * DFFN, wh, wm, wl);
        k_gemm6<0, 0><<<dim3(4, M / 128), dim3(256), 0, stream>>>(
            S1, DFFN, wh, wm, wl, b2 + l * DMODEL, S0, DMODEL, DFFN, 1, 1);
        k_ln<<<dim3(M), dim3(128), 0, stream>>>(S3, S0, ln2g + l * DMODEL, ln2b + l * DMODEL, S1);

        xin = S1;
        Tin = Tout;
    }

    // ---- VQ: split x (S1) and codebook to bf16 hi/lo in freed scratch (S2, S3).
    // cand (64 splits x NROWS float4 = 12.85 MB) lives in freed S0.
    unsigned short* xh = (unsigned short*)S2;
    unsigned short* xl = xh + (size_t)NROWS * DMODEL;
    unsigned short* chb = (unsigned short*)S3;
    unsigned short* clb = chb + (size_t)KCB * DMODEL;
    float4* cand = (float4*)S0;
    k_split<<<dim3(NROWS * DMODEL / 4 / 256), dim3(256), 0, stream>>>(S1, xh, xl,
                                                                      NROWS * DMODEL / 4);
    k_split<<<dim3(KCB * DMODEL / 4 / 256), dim3(256), 0, stream>>>(cb, chb, clb,
                                                                    KCB * DMODEL / 4);

    float* outq = (float*)d_out;
    float* outi = outq + (size_t)NROWS * DMODEL;
    k_vq1m<<<dim3(98 * NSPLIT), dim3(256), 0, stream>>>(xh, xl, chb, clb, cbn, cand);
    k_vq2<<<dim3(49), dim3(256), 0, stream>>>(cand, idxbuf, flagbuf, NROWS);
    // cbT overwrites chb/clb region (dead after vq1m) — stream order guarantees safety
    float* cbT = (float*)S3;
    k_cbT<<<dim3(KCB / 64, DMODEL / 64), dim3(256), 0, stream>>>(cb, cbT);
    k_vq3<<<dim3(NROWS), dim3(256), 0, stream>>>(S1, cb, cbT, cbn, idxbuf, flagbuf, outq, outi);
}

// Round 7
// 3486.535 us; speedup vs baseline: 1.5836x; 1.0954x over previous
//
#include <hip/hip_runtime.h>
#include <hip/hip_bf16.h>
#include <math.h>

#define BBATCH 256
#define DMODEL 512
#define NHEAD 4
#define DHEAD 128
#define DFFN 1024
#define KCB 8192
#define VEPS 0.02f
#define NROWS 12544
#define NSPLIT 64   // 8192 / 128 code tiles

typedef __attribute__((ext_vector_type(8))) short short8v;   // 8 bf16 in 4 VGPRs
typedef __attribute__((ext_vector_type(4))) float f32x4;

// ---------------- exact 3-way truncation split: x == hi + mid + lo (24 mantissa bits)
__device__ __forceinline__ void tsplit3(float x, unsigned short& h,
                                        unsigned short& m, unsigned short& l) {
    unsigned u = __float_as_uint(x);
    float hf = __uint_as_float(u & 0xffff0000u);
    float r = x - hf;                       // exact
    unsigned ru = __float_as_uint(r);
    float mf = __uint_as_float(ru & 0xffff0000u);
    float r2 = r - mf;                      // exact
    h = (unsigned short)(u >> 16);
    m = (unsigned short)(ru >> 16);
    l = (unsigned short)(__float_as_uint(r2) >> 16);
}

// ---------------- weight transpose + 3-way split: W[K][N] (ldw) -> [N][K] bf16 h/m/l
__global__ __launch_bounds__(256) void k_wsplit3T(const float* __restrict__ W, int ldw,
                                                  int K, int total,
                                                  unsigned short* __restrict__ th,
                                                  unsigned short* __restrict__ tm,
                                                  unsigned short* __restrict__ tl) {
    int idx = blockIdx.x * 256 + threadIdx.x;
    if (idx >= total) return;
    int n = idx / K, k = idx - n * K;
    unsigned short h, m, l;
    tsplit3(W[(size_t)k * ldw + n], h, m, l);
    th[idx] = h; tm[idx] = m; tl[idx] = l;
}

// ---------------- conv weight: cw[dout][di][kk] -> [dout][k=kk*512+di] bf16 h/m/l
__global__ __launch_bounds__(256) void k_wsplit3_conv(const float* __restrict__ cw,
                                                      unsigned short* __restrict__ th,
                                                      unsigned short* __restrict__ tm,
                                                      unsigned short* __restrict__ tl) {
    int idx = blockIdx.x * 256 + threadIdx.x;
    if (idx >= DMODEL * 3 * DMODEL) return;
    int dout = idx / 1536, k = idx - dout * 1536;
    int kk = k >> 9, di = k & 511;
    unsigned short h, m, l;
    tsplit3(cw[(size_t)dout * 1536 + di * 3 + kk], h, m, l);
    th[idx] = h; tm[idx] = m; tl[idx] = l;
}

// ---------------- 9-term split-bf16 MFMA GEMM: exact fp32-grade numerics.
// C[M][N] = act(A[M][K] @ Bt^T + bias); Bt = [N][K] pre-split h/m/l; A split in-staging.
// 128x128 tile, BK=32, 4 waves 2x2 (64x64, 4x4 f32x4 accs). LDS 6x8KB, swizzle
// seg^((row>>1)&3) on write+read (2-way conflicts = free). ACT: 0 none,1 GELU,2 relu.
template <int ACT, int CONV>
__global__ __launch_bounds__(256) void k_gemm6(const float* __restrict__ A, int lda,
                                               const unsigned short* __restrict__ B3h,
                                               const unsigned short* __restrict__ B3m,
                                               const unsigned short* __restrict__ B3l,
                                               const float* __restrict__ bias,
                                               float* __restrict__ C, int ldc,
                                               int K, int Tin, int Tout) {
    __shared__ __align__(16) unsigned short Ah[4096], Am[4096], Al[4096];
    __shared__ __align__(16) unsigned short Bh[4096], Bm[4096], Bl[4096];

    int tid = threadIdx.x;
    int lane = tid & 63, wave = tid >> 6;
    int lrow = lane & 15, lkg = lane >> 4;
    int wr = wave >> 1, wc = wave & 1;
    int wrbase = wr * 64, wcbase = wc * 64;
    int n0 = blockIdx.x * 128, m0 = blockIdx.y * 128;

    int sr[2], ss[2]; size_t abase[2], bbase[2]; int attv[2];
#pragma unroll
    for (int rd = 0; rd < 2; rd++) {
        int slot = tid + rd * 256;
        int row = slot >> 2, seg = slot & 3;
        sr[rd] = row; ss[rd] = seg;
        bbase[rd] = (size_t)(n0 + row) * K + seg * 8;
        int m = m0 + row;
        if (CONV) {
            int b = m / Tout, tt = m - b * Tout;
            abase[rd] = (size_t)b * Tin * DMODEL;
            attv[rd] = 2 * tt - 2;
        } else {
            abase[rd] = (size_t)m * lda + seg * 8;
            attv[rd] = 0;
        }
    }

    f32x4 acc[4][4];
#pragma unroll
    for (int mi = 0; mi < 4; mi++)
#pragma unroll
        for (int ni = 0; ni < 4; ni++) acc[mi][ni] = (f32x4){0.0f, 0.0f, 0.0f, 0.0f};

    for (int k0 = 0; k0 < K; k0 += 32) {
#pragma unroll
        for (int rd = 0; rd < 2; rd++) {
            int row = sr[rd], seg = ss[rd];
            int la = row * 32 + ((seg ^ ((row >> 1) & 3)) << 3);
            *(short8v*)(Bh + la) = *(const short8v*)(B3h + bbase[rd] + k0);
            *(short8v*)(Bm + la) = *(const short8v*)(B3m + bbase[rd] + k0);
            *(short8v*)(Bl + la) = *(const short8v*)(B3l + bbase[rd] + k0);
            const float* ap;
            if (CONV) {
                int f = attv[rd] + (k0 >> 9);
                if (f < 0) f = 0;
                ap = A + abase[rd] + (size_t)f * DMODEL + (k0 & 511) + seg * 8;
            } else {
                ap = A + abase[rd] + k0;
            }
            float4 v0 = *(const float4*)ap;
            float4 v1 = *(const float4*)(ap + 4);
            float vv[8] = {v0.x, v0.y, v0.z, v0.w, v1.x, v1.y, v1.z, v1.w};
            short8v hv, mv, lv;
#pragma unroll
            for (int j = 0; j < 8; j++) {
                unsigned short h, m, l;
                tsplit3(vv[j], h, m, l);
                hv[j] = (short)h; mv[j] = (short)m; lv[j] = (short)l;
            }
            *(short8v*)(Ah + la) = hv;
            *(short8v*)(Am + la) = mv;
            *(short8v*)(Al + la) = lv;
        }
        __syncthreads();

        short8v afh[4], afm[4], afl[4];
#pragma unroll
        for (int mi = 0; mi < 4; mi++) {
            int rowa = wrbase + mi * 16 + lrow;
            int off = rowa * 32 + ((lkg ^ ((rowa >> 1) & 3)) << 3);
            afh[mi] = *(const short8v*)(Ah + off);
            afm[mi] = *(const short8v*)(Am + off);
            afl[mi] = *(const short8v*)(Al + off);
        }
#pragma unroll
        for (int ni = 0; ni < 4; ni++) {
            int rowb = wcbase + ni * 16 + lrow;
            int off = rowb * 32 + ((lkg ^ ((rowb >> 1) & 3)) << 3);
            short8v bfh = *(const short8v*)(Bh + off);
            short8v bfm = *(const short8v*)(Bm + off);
            short8v bfl = *(const short8v*)(Bl + off);
#pragma unroll
            for (int mi = 0; mi < 4; mi++) {
                acc[mi][ni] = __builtin_amdgcn_mfma_f32_16x16x32_bf16(afh[mi], bfh, acc[mi][ni], 0, 0, 0);
                acc[mi][ni] = __builtin_amdgcn_mfma_f32_16x16x32_bf16(afh[mi], bfm, acc[mi][ni], 0, 0, 0);
                acc[mi][ni] = __builtin_amdgcn_mfma_f32_16x16x32_bf16(afm[mi], bfh, acc[mi][ni], 0, 0, 0);
                acc[mi][ni] = __builtin_amdgcn_mfma_f32_16x16x32_bf16(afh[mi], bfl, acc[mi][ni], 0, 0, 0);
                acc[mi][ni] = __builtin_amdgcn_mfma_f32_16x16x32_bf16(afl[mi], bfh, acc[mi][ni], 0, 0, 0);
                acc[mi][ni] = __builtin_amdgcn_mfma_f32_16x16x32_bf16(afm[mi], bfm, acc[mi][ni], 0, 0, 0);
                acc[mi][ni] = __builtin_amdgcn_mfma_f32_16x16x32_bf16(afm[mi], bfl, acc[mi][ni], 0, 0, 0);
                acc[mi][ni] = __builtin_amdgcn_mfma_f32_16x16x32_bf16(afl[mi], bfm, acc[mi][ni], 0, 0, 0);
                acc[mi][ni] = __builtin_amdgcn_mfma_f32_16x16x32_bf16(afl[mi], bfl, acc[mi][ni], 0, 0, 0);
            }
        }
        __syncthreads();
    }

    float bv[4];
#pragma unroll
    for (int ni = 0; ni < 4; ni++) bv[ni] = bias[n0 + wcbase + ni * 16 + lrow];
#pragma unroll
    for (int mi = 0; mi < 4; mi++)
#pragma unroll
        for (int ni = 0; ni < 4; ni++)
#pragma unroll
            for (int v = 0; v < 4; v++) {
                int row = m0 + wrbase + mi * 16 + lkg * 4 + v;
                int col = n0 + wcbase + ni * 16 + lrow;
                float x;
                if (ACT == 1) {
                    double dv = (double)acc[mi][ni][v] + (double)bv[ni];
                    dv = 0.5 * dv * (1.0 + erf(dv * 0.7071067811865476));
                    x = (float)dv;
                } else {
                    x = acc[mi][ni][v] + bv[ni];
                    if (ACT == 2) x = x > 0.0f ? x : 0.0f;
                }
                C[(size_t)row * ldc + col] = x;
            }
}

// ---------------- attention v3: one block per (h, b); 4 waves; 4 rows per iteration.
// K in LDS with row-quad XOR swizzle (b128 conflict-free); q staged cooperatively
// (uniform LDS reads, no readlane); p via per-wave LDS; 4-way ILP in QK and PV.
// Exact fp32 numerics. out may alias q.
__global__ __launch_bounds__(256) void k_attn(const float* q,
                                              const float* __restrict__ k,
                                              const float* __restrict__ v,
                                              float* out, int T) {
    __shared__ __align__(16) float Ks[98 * 128];     // swizzled, row stride 512B
    __shared__ __align__(16) float qsm[4][128];
    __shared__ float psm[4][128];
    int h = blockIdx.x, b = blockIdx.y;
    int tid = threadIdx.x;
    int lane = tid & 63;
    int wave = tid >> 6;
    size_t base = ((size_t)b * T) * DMODEL + (size_t)h * DHEAD;

    float4* Ks4 = (float4*)Ks;
    for (int it = tid; it < T * 32; it += 256) {
        int j = it >> 5, dq = it & 31;
        Ks4[j * 32 + (dq ^ (j & 7))] =
            *(const float4*)&k[base + (size_t)j * DMODEL + dq * 4];
    }
    __syncthreads();

    const float SCALE = 0.08838834764831845f;  // 1/sqrt(128)
    int niter = (T + 3) >> 2;
    for (int i0 = 0; i0 < niter; i0++) {
        int ibase = i0 * 4;
        // cooperative staging of the 4 q rows this iteration consumes
#pragma unroll
        for (int u = 0; u < 2; u++) {
            int idx = tid + u * 256;
            int r = idx >> 7, d = idx & 127;
            int grow = ibase + r;
            if (grow < T) qsm[r][d] = q[base + (size_t)grow * DMODEL + d];
        }
        __syncthreads();

        int i = ibase + wave;
        if (i < T) {
            int j1 = lane;
            int j2 = lane + 64;
            int j2c = j2 < T ? j2 : 0;
            bool a0 = (j1 <= i);
            bool a1 = (j2 <= i);
            const float4* kr1 = Ks4 + j1 * 32;
            const float4* kr2 = Ks4 + j2c * 32;
            const float4* qr = (const float4*)qsm[wave];
            int x1 = j1 & 7, x2 = j2c & 7;
            float4 s0 = {0.f, 0.f, 0.f, 0.f}, s1 = {0.f, 0.f, 0.f, 0.f};
#pragma unroll
            for (int dq = 0; dq < 32; dq++) {
                float4 qv = qr[dq];
                float4 k1 = kr1[dq ^ x1];
                float4 k2 = kr2[dq ^ x2];
                s0.x = fmaf(qv.x, k1.x, s0.x);
                s0.y = fmaf(qv.y, k1.y, s0.y);
                s0.z = fmaf(qv.z, k1.z, s0.z);
                s0.w = fmaf(qv.w, k1.w, s0.w);
                s1.x = fmaf(qv.x, k2.x, s1.x);
                s1.y = fmaf(qv.y, k2.y, s1.y);
                s1.z = fmaf(qv.z, k2.z, s1.z);
                s1.w = fmaf(qv.w, k2.w, s1.w);
            }
            float sv0 = a0 ? ((s0.x + s0.y) + (s0.z + s0.w)) * SCALE : -1e30f;
            float sv1 = a1 ? ((s1.x + s1.y) + (s1.z + s1.w)) * SCALE : -1e30f;

            float m = fmaxf(sv0, sv1);
#pragma unroll
            for (int off = 32; off > 0; off >>= 1) m = fmaxf(m, __shfl_xor(m, off, 64));
            float p0 = a0 ? expf(sv0 - m) : 0.0f;
            float p1 = a1 ? expf(sv1 - m) : 0.0f;
            float sum = p0 + p1;
#pragma unroll
            for (int off = 32; off > 0; off >>= 1) sum += __shfl_xor(sum, off, 64);
            float inv = 1.0f / sum;

            // per-wave p buffer: slots > i hold exact 0 -> branch-free 4-unroll below
            psm[wave][lane] = p0;
            psm[wave][lane + 64] = p1;

            float o0[4] = {0.f, 0.f, 0.f, 0.f}, o1[4] = {0.f, 0.f, 0.f, 0.f};
            const float* vb = v + base;
            for (int j = 0; j <= i; j += 4) {
#pragma unroll
                for (int u = 0; u < 4; u++) {
                    int jj = j + u;
                    float pj = psm[wave][jj];          // 0 beyond i
                    int jr = jj < T ? jj : T - 1;      // keep address in-bounds
                    const float* vr = vb + (size_t)jr * DMODEL;
                    o0[u] = fmaf(pj, vr[lane], o0[u]);
                    o1[u] = fmaf(pj, vr[lane + 64], o1[u]);
                }
            }
            out[base + (size_t)i * DMODEL + lane] =
                ((o0[0] + o0[1]) + (o0[2] + o0[3])) * inv;
            out[base + (size_t)i * DMODEL + lane + 64] =
                ((o1[0] + o1[1]) + (o1[2] + o1[3])) * inv;
        }
        __syncthreads();
    }
}

// ---------------- fused residual-add + LayerNorm
__global__ __launch_bounds__(128) void k_ln(const float* __restrict__ resid,
                                            const float* __restrict__ y,
                                            const float* __restrict__ g,
                                            const float* __restrict__ bta,
                                            float* __restrict__ out) {
    int row = blockIdx.x;
    int tid = threadIdx.x;
    size_t off = (size_t)row * DMODEL;
    double t[4];
#pragma unroll
    for (int i = 0; i < 4; i++) {
        int d = tid + i * 128;
        t[i] = (double)resid[off + d] + (double)y[off + d];
    }
    __shared__ double rd[2];
    double s = t[0] + t[1] + t[2] + t[3];
#pragma unroll
    for (int o = 32; o > 0; o >>= 1) s += __shfl_down(s, o, 64);
    if ((tid & 63) == 0) rd[tid >> 6] = s;
    __syncthreads();
    double mean = (rd[0] + rd[1]) * (1.0 / 512.0);
    double vs = 0.0;
#pragma unroll
    for (int i = 0; i < 4; i++) { double dl = t[i] - mean; vs += dl * dl; }
    __syncthreads();
#pragma unroll
    for (int o = 32; o > 0; o >>= 1) vs += __shfl_down(vs, o, 64);
    if ((tid & 63) == 0) rd[tid >> 6] = vs;
    __syncthreads();
    double var = (rd[0] + rd[1]) * (1.0 / 512.0);
    double scale = 1.0 / sqrt(var + 1e-5);
#pragma unroll
    for (int i = 0; i < 4; i++) {
        int d = tid + i * 128;
        out[off + d] = (float)((t[i] - mean) * scale * (double)g[d] + (double)bta[d]);
    }
}

// ---------------- codebook squared norms (fp64)
__global__ __launch_bounds__(64) void k_cbn(const float* __restrict__ cb,
                                            double* __restrict__ cbn) {
    int row = blockIdx.x;
    int tid = threadIdx.x;
    const float* r = cb + (size_t)row * DMODEL;
    double s = 0.0;
    for (int d = tid; d < DMODEL; d += 64) { double v = (double)r[d]; s = fma(v, v, s); }
#pragma unroll
    for (int o = 32; o > 0; o >>= 1) s += __shfl_down(s, o, 64);
    if (tid == 0) cbn[row] = s;
}

// ---------------- split fp32 -> (bf16 hi, bf16 lo residual), RNE (VQ path, verified)
__device__ __forceinline__ unsigned short f2bf(float f) {
    unsigned u = __float_as_uint(f);
    unsigned r = (u + 0x7fffu + ((u >> 16) & 1u)) >> 16;
    return (unsigned short)r;
}
__device__ __forceinline__ float bf2f(unsigned short h) {
    return __uint_as_float(((unsigned)h) << 16);
}

__global__ __launch_bounds__(256) void k_split(const float* __restrict__ in,
                                               unsigned short* __restrict__ hi,
                                               unsigned short* __restrict__ lo,
                                               int n4) {
    int i = blockIdx.x * 256 + threadIdx.x;
    if (i >= n4) return;
    float4 v = ((const float4*)in)[i];
    float vv[4] = {v.x, v.y, v.z, v.w};
    unsigned short h[4], l[4];
#pragma unroll
    for (int j = 0; j < 4; j++) {
        h[j] = f2bf(vv[j]);
        l[j] = f2bf(vv[j] - bf2f(h[j]));
    }
    ((ushort4*)hi)[i] = make_ushort4(h[0], h[1], h[2], h[3]);
    ((ushort4*)lo)[i] = make_ushort4(l[0], l[1], l[2], l[3]);
}

// ---------------- codebook transpose: cbT[d][c] = cb[c][d] (LDS-tiled, coalesced)
__global__ __launch_bounds__(256) void k_cbT(const float* __restrict__ cb,
                                             float* __restrict__ cbT) {
    __shared__ float t[64][65];
    int c0 = blockIdx.x * 64, d0 = blockIdx.y * 64;
    int tid = threadIdx.x;
#pragma unroll
    for (int i = 0; i < 16; i++) {
        int e = tid + i * 256;
        t[e >> 6][e & 63] = cb[(size_t)(c0 + (e >> 6)) * DMODEL + d0 + (e & 63)];
    }
    __syncthreads();
#pragma unroll
    for (int i = 0; i < 16; i++) {
        int e = tid + i * 256;
        int d = e >> 6, c = e & 63;
        cbT[(size_t)(d0 + d) * KCB + c0 + c] = t[c][d];
    }
}

// ---------------- VQ phase 1: split-bf16 MFMA GEMM, LDS-staged (verified r3/r5/r6).
__global__ __launch_bounds__(256) void k_vq1m(const unsigned short* __restrict__ xh,
                                              const unsigned short* __restrict__ xl,
                                              const unsigned short* __restrict__ ch,
                                              const unsigned short* __restrict__ cl,
                                              const double* __restrict__ cbn,
                                              float4* __restrict__ cand) {
    __shared__ __align__(16) unsigned char smem[65536];
    unsigned short* AhU = (unsigned short*)smem;           // [128][64]
    unsigned short* AlU = AhU + 8192;
    unsigned short* BhU = AlU + 8192;
    unsigned short* BlU = BhU + 8192;

    int tid = threadIdx.x;
    int lane = tid & 63, wave = tid >> 6;
    int lrow = lane & 15;
    int lkg = lane >> 4;
    int wr = wave >> 1, wc = wave & 1;
    int wrbase = wr * 64, wcbase = wc * 64;

    int wg = (blockIdx.x & 7) * (6272 / 8) + (blockIdx.x >> 3);
    int bx = wg / 98;
    int by = wg % 98;
    int r0 = by * 128, c0 = bx * 128;

    const int srow = tid >> 3;
    const int seg = tid & 7;
    const int sw = seg ^ (srow & 7);

    f32x4 acc[4][4];
#pragma unroll
    for (int m = 0; m < 4; m++)
#pragma unroll
        for (int n = 0; n < 4; n++) acc[m][n] = (f32x4){0.0f, 0.0f, 0.0f, 0.0f};

    for (int ks = 0; ks < 8; ks++) {
        int k0 = ks * 64;
#pragma unroll
        for (int rd = 0; rd < 4; rd++) {
            int row = rd * 32 + srow;
            size_t ga = (((size_t)(r0 + row)) << 9) + k0 + seg * 8;
            size_t gb = (((size_t)(c0 + row)) << 9) + k0 + seg * 8;
            int la = row * 64 + sw * 8;
            *(short8v*)(AhU + la) = *(const short8v*)(xh + ga);
            *(short8v*)(AlU + la) = *(const short8v*)(xl + ga);
            *(short8v*)(BhU + la) = *(const short8v*)(ch + gb);
            *(short8v*)(BlU + la) = *(const short8v*)(cl + gb);
        }
        __syncthreads();
#pragma unroll
        for (int ksub = 0; ksub < 2; ksub++) {
            int segsw = ((ksub * 4 + lkg) ^ (lrow & 7)) * 8;
            short8v afh[4], afl[4], bfh[4], bfl[4];
#pragma unroll
            for (int m = 0; m < 4; m++) {
                int off = (wrbase + m * 16 + lrow) * 64 + segsw;
                afh[m] = *(const short8v*)(AhU + off);
                afl[m] = *(const short8v*)(AlU + off);
            }
#pragma unroll
            for (int n = 0; n < 4; n++) {
                int off = (wcbase + n * 16 + lrow) * 64 + segsw;
                bfh[n] = *(const short8v*)(BhU + off);
                bfl[n] = *(const short8v*)(BlU + off);
            }
#pragma unroll
            for (int m = 0; m < 4; m++)
#pragma unroll
                for (int n = 0; n < 4; n++) {
                    acc[m][n] = __builtin_amdgcn_mfma_f32_16x16x32_bf16(afh[m], bfh[n], acc[m][n], 0, 0, 0);
                    acc[m][n] = __builtin_amdgcn_mfma_f32_16x16x32_bf16(afh[m], bfl[n], acc[m][n], 0, 0, 0);
                    acc[m][n] = __builtin_amdgcn_mfma_f32_16x16x32_bf16(afl[m], bfh[n], acc[m][n], 0, 0, 0);
                }
        }
        __syncthreads();
    }

    float cnv[4];
#pragma unroll
    for (int n = 0; n < 4; n++) cnv[n] = (float)cbn[c0 + wcbase + n * 16 + lrow];

    float* sD = (float*)smem;
    int* sI = (int*)(smem + 32768);
#pragma unroll
    for (int m = 0; m < 4; m++)
#pragma unroll
        for (int v = 0; v < 4; v++) {
            int row = wrbase + m * 16 + lkg * 4 + v;
            float d1 = 1e30f, d2 = 1e30f; int j1 = 0, j2 = 0;
#pragma unroll
            for (int n = 0; n < 4; n++) {
                int code = c0 + wcbase + n * 16 + lrow;
                float d = cnv[n] - 2.0f * acc[m][n][v];
                if (d < d1 || (d == d1 && code < j1)) { d2 = d1; j2 = j1; d1 = d; j1 = code; }
                else if (d < d2 || (d == d2 && code < j2)) { d2 = d; j2 = code; }
            }
            int slot = (wc * 16 + lrow) * 2;
            sD[row * 64 + slot] = d1; sD[row * 64 + slot + 1] = d2;
            sI[row * 64 + slot] = j1; sI[row * 64 + slot + 1] = j2;
        }
    __syncthreads();
    if (tid < 128) {
        float d1 = 1e30f, d2 = 1e30f; int j1 = 0, j2 = 0;
        for (int e = 0; e < 64; e++) {
            float d = sD[tid * 64 + e]; int ix = sI[tid * 64 + e];
            if (d < d1 || (d == d1 && ix < j1)) { d2 = d1; j2 = j1; d1 = d; j1 = ix; }
            else if (d < d2 || (d == d2 && ix < j2)) { d2 = d; j2 = ix; }
        }
        cand[(size_t)bx * NROWS + r0 + tid] =
            make_float4(d1, __int_as_float(j1), d2, __int_as_float(j2));
    }
}

// ---------------- VQ phase 2: merge 64 splits' top-2; flag near-ties
__global__ __launch_bounds__(256) void k_vq2(const float4* __restrict__ cand,
                                             int* __restrict__ idxbuf,
                                             int* __restrict__ flagbuf, int nrows) {
    int row = blockIdx.x * 256 + threadIdx.x;
    if (row >= nrows) return;
    float d1 = 1e30f, d2 = 1e30f; int j1 = 0, j2 = 0;
    for (int s = 0; s < NSPLIT; s++) {
        float4 c = cand[(size_t)s * nrows + row];
        float dd[2] = {c.x, c.z};
        int ii[2] = {__float_as_int(c.y), __float_as_int(c.w)};
#pragma unroll
        for (int e = 0; e < 2; e++) {
            float d = dd[e]; int ix = ii[e];
            if (d < d1 || (d == d1 && ix < j1)) { d2 = d1; j2 = j1; d1 = d; j1 = ix; }
            else if (d < d2 || (d == d2 && ix < j2)) { d2 = d; j2 = ix; }
        }
    }
    idxbuf[row] = j1;
    flagbuf[row] = (d2 - d1 < VEPS) ? 1 : 0;
}

// ---------------- VQ phase 3: exact fp64 rescan via TRANSPOSED codebook (coalesced)
__global__ __launch_bounds__(256) void k_vq3(const float* __restrict__ x,
                                             const float* __restrict__ cb,
                                             const float* __restrict__ cbT,
                                             const double* __restrict__ cbn,
                                             const int* __restrict__ idxbuf,
                                             const int* __restrict__ flagbuf,
                                             float* __restrict__ outq,
                                             float* __restrict__ outi) {
    int row = blockIdx.x;
    int tid = threadIdx.x;
    int best = idxbuf[row];
    if (flagbuf[row]) {
        __shared__ __align__(16) float xs[DMODEL];
        __shared__ double sd[256];
        __shared__ int si[256];
        xs[tid] = x[(size_t)row * DMODEL + tid];
        xs[tid + 256] = x[(size_t)row * DMODEL + tid + 256];
        __syncthreads();
        double bd = 1e300; int bi = 0x7fffffff;
        const float4* xs4 = (const float4*)xs;
        for (int c0 = 0; c0 < KCB; c0 += 256) {
            int c = c0 + tid;
            double a0 = 0.0, a1 = 0.0, a2 = 0.0, a3 = 0.0;
#pragma unroll 8
            for (int q = 0; q < DMODEL / 4; q++) {
                float4 xv = xs4[q];
                const float* cp = cbT + (size_t)(q * 4) * KCB + c;
                a0 = fma((double)xv.x, (double)cp[0], a0);
                a1 = fma((double)xv.y, (double)cp[KCB], a1);
                a2 = fma((double)xv.z, (double)cp[2 * KCB], a2);
                a3 = fma((double)xv.w, (double)cp[3 * KCB], a3);
            }
            double dist = cbn[c] - 2.0 * ((a0 + a1) + (a2 + a3));
            if (dist < bd || (dist == bd && c < bi)) { bd = dist; bi = c; }
        }
        sd[tid] = bd; si[tid] = bi;
        __syncthreads();
        for (int off = 128; off > 0; off >>= 1) {
            if (tid < off) {
                if (sd[tid + off] < sd[tid] ||
                    (sd[tid + off] == sd[tid] && si[tid + off] < si[tid])) {
                    sd[tid] = sd[tid + off]; si[tid] = si[tid + off];
                }
            }
            __syncthreads();
        }
        best = si[0];
    }
    const float* crow = cb + (size_t)best * DMODEL;
    outq[(size_t)row * DMODEL + tid] = crow[tid];
    outq[(size_t)row * DMODEL + tid + 256] = crow[tid + 256];
    if (tid == 0) outi[row] = (float)best;
}

extern "C" void kernel_launch(void* const* d_in, const int* in_sizes, int n_in,
                              void* d_out, int out_size, void* d_ws, size_t ws_size,
                              hipStream_t stream) {
    const float* motion = (const float*)d_in[0];
    const float* conv_w = (const float*)d_in[1];
    const float* conv_b = (const float*)d_in[2];
    const float* wqkv   = (const float*)d_in[3];
    const float* bqkv   = (const float*)d_in[4];
    const float* wo     = (const float*)d_in[5];
    const float* bo     = (const float*)d_in[6];
    const float* ln1g   = (const float*)d_in[7];
    const float* ln1b   = (const float*)d_in[8];
    const float* ln2g   = (const float*)d_in[9];
    const float* ln2b   = (const float*)d_in[10];
    const float* w1     = (const float*)d_in[11];
    const float* b1     = (const float*)d_in[12];
    const float* w2     = (const float*)d_in[13];
    const float* b2     = (const float*)d_in[14];
    const float* cb     = (const float*)d_in[15];

    const size_t SZc = (size_t)25088 * DMODEL;
    float* wsf = (float*)d_ws;
    float*  S0  = wsf + 0 * SZc;
    float*  S1  = wsf + 1 * SZc;
    float*  S2  = wsf + 2 * SZc;
    float*  S3  = wsf + 3 * SZc;
    char* p = (char*)(wsf + 4 * SZc);
    unsigned short* wh = (unsigned short*)p;   p += (size_t)786432 * 2;
    unsigned short* wm = (unsigned short*)p;   p += (size_t)786432 * 2;
    unsigned short* wl = (unsigned short*)p;   p += (size_t)786432 * 2;
    double* cbn   = (double*)p;                p += KCB * 8;
    int*   idxbuf = (int*)p;                   p += NROWS * 4;
    int*   flagbuf= (int*)p;

    k_cbn<<<dim3(KCB), dim3(64), 0, stream>>>(cb, cbn);

    const float* xin = motion;
    int Tin = 196;
    for (int l = 0; l < 2; l++) {
        int Tout = Tin / 2;            // 98, then 49
        int M = BBATCH * Tout;         // 25088, then 12544
        const float* wq = wqkv + (size_t)l * DMODEL * 3 * DMODEL;
        const float* bq = bqkv + (size_t)l * 3 * DMODEL;

        // conv (fused gather + exact fp64 GELU epilogue)
        k_wsplit3_conv<<<dim3(3072), dim3(256), 0, stream>>>(
            conv_w + (size_t)l * DMODEL * DMODEL * 3, wh, wm, wl);
        k_gemm6<1, 1><<<dim3(4, M / 128), dim3(256), 0, stream>>>(
            xin, DMODEL, wh, wm, wl, conv_b + l * DMODEL, S0, DMODEL,
            3 * DMODEL, Tin, Tout);
        // qkv
        float* qkvdst[3] = {S1, S2, S3};
        for (int s = 0; s < 3; s++) {
            k_wsplit3T<<<dim3(1024), dim3(256), 0, stream>>>(
                wq + s * DMODEL, 3 * DMODEL, DMODEL, DMODEL * DMODEL, wh, wm, wl);
            k_gemm6<0, 0><<<dim3(4, M / 128), dim3(256), 0, stream>>>(
                S0, DMODEL, wh, wm, wl, bq + s * DMODEL, qkvdst[s], DMODEL,
                DMODEL, 1, 1);
        }
        k_attn<<<dim3(NHEAD, BBATCH), dim3(256), 0, stream>>>(S1, S2, S3, S1, Tout);
        // wo
        k_wsplit3T<<<dim3(1024), dim3(256), 0, stream>>>(
            wo + (size_t)l * DMODEL * DMODEL, DMODEL, DMODEL, DMODEL * DMODEL, wh, wm, wl);
        k_gemm6<0, 0><<<dim3(4, M / 128), dim3(256), 0, stream>>>(
            S1, DMODEL, wh, wm, wl, bo + l * DMODEL, S2, DMODEL, DMODEL, 1, 1);
        k_ln<<<dim3(M), dim3(128), 0, stream>>>(S0, S2, ln1g + l * DMODEL, ln1b + l * DMODEL, S3);
        // ffn
        k_wsplit3T<<<dim3(2048), dim3(256), 0, stream>>>(
            w1 + (size_t)l * DMODEL * DFFN, DFFN, DMODEL, DMODEL * DFFN, wh, wm, wl);
        k_gemm6<2, 0><<<dim3(8, M / 128), dim3(256), 0, stream>>>(
            S3, DMODEL, wh, wm, wl, b1 + l * DFFN, S1, DFFN, DMODEL, 1, 1);
        k_wsplit3T<<<dim3(2048), dim3(256), 0, stream>>>(
            w2 + (size_t)l * DFFN * DMODEL, DMODEL, DFFN, DMODEL * DFFN, wh, wm, wl);
        k_gemm6<0, 0><<<dim3(4, M / 128), dim3(256), 0, stream>>>(
            S1, DFFN, wh, wm, wl, b2 + l * DMODEL, S0, DMODEL, DFFN, 1, 1);
        k_ln<<<dim3(M), dim3(128), 0, stream>>>(S3, S0, ln2g + l * DMODEL, ln2b + l * DMODEL, S1);

        xin = S1;
        Tin = Tout;
    }

    // ---- VQ: split x (S1) and codebook to bf16 hi/lo in freed scratch (S2, S3).
    // cand (64 splits x NROWS float4 = 12.85 MB) lives in freed S0.
    unsigned short* xh = (unsigned short*)S2;
    unsigned short* xl = xh + (size_t)NROWS * DMODEL;
    unsigned short* chb = (unsigned short*)S3;
    unsigned short* clb = chb + (size_t)KCB * DMODEL;
    float4* cand = (float4*)S0;
    k_split<<<dim3(NROWS * DMODEL / 4 / 256), dim3(256), 0, stream>>>(S1, xh, xl,
                                                                      NROWS * DMODEL / 4);
    k_split<<<dim3(KCB * DMODEL / 4 / 256), dim3(256), 0, stream>>>(cb, chb, clb,
                                                                    KCB * DMODEL / 4);

    float* outq = (float*)d_out;
    float* outi = outq + (size_t)NROWS * DMODEL;
    k_vq1m<<<dim3(98 * NSPLIT), dim3(256), 0, stream>>>(xh, xl, chb, clb, cbn, cand);
    k_vq2<<<dim3(49), dim3(256), 0, stream>>>(cand, idxbuf, flagbuf, NROWS);
    // cbT overwrites chb/clb region (dead after vq1m) — stream order guarantees safety
    float* cbT = (float*)S3;
    k_cbT<<<dim3(KCB / 64, DMODEL / 64), dim3(256), 0, stream>>>(cb, cbT);
    k_vq3<<<dim3(NROWS), dim3(256), 0, stream>>>(S1, cb, cbT, cbn, idxbuf, flagbuf, outq, outi);
}

// Round 8
// 2697.872 us; speedup vs baseline: 2.0466x; 1.2923x over previous
//
#include <hip/hip_runtime.h>
#include <hip/hip_bf16.h>
#include <math.h>

#define BBATCH 256
#define DMODEL 512
#define NHEAD 4
#define DHEAD 128
#define DFFN 1024
#define KCB 8192
#define VEPS 0.02f
#define NROWS 12544
#define NSPLIT 64   // 8192 / 128 code tiles

typedef __attribute__((ext_vector_type(8))) short short8v;   // 8 bf16 in 4 VGPRs
typedef __attribute__((ext_vector_type(4))) float f32x4;

// ---------------- exact 3-way truncation split: x == hi + mid + lo (24 mantissa bits)
__device__ __forceinline__ void tsplit3(float x, unsigned short& h,
                                        unsigned short& m, unsigned short& l) {
    unsigned u = __float_as_uint(x);
    float hf = __uint_as_float(u & 0xffff0000u);
    float r = x - hf;                       // exact
    unsigned ru = __float_as_uint(r);
    float mf = __uint_as_float(ru & 0xffff0000u);
    float r2 = r - mf;                      // exact
    h = (unsigned short)(u >> 16);
    m = (unsigned short)(ru >> 16);
    l = (unsigned short)(__float_as_uint(r2) >> 16);
}

// ---------------- weight transpose + 3-way split: W[K][N] (ldw) -> [N][K] bf16 h/m/l
__global__ __launch_bounds__(256) void k_wsplit3T(const float* __restrict__ W, int ldw,
                                                  int K, int total,
                                                  unsigned short* __restrict__ th,
                                                  unsigned short* __restrict__ tm,
                                                  unsigned short* __restrict__ tl) {
    int idx = blockIdx.x * 256 + threadIdx.x;
    if (idx >= total) return;
    int n = idx / K, k = idx - n * K;
    unsigned short h, m, l;
    tsplit3(W[(size_t)k * ldw + n], h, m, l);
    th[idx] = h; tm[idx] = m; tl[idx] = l;
}

// ---------------- conv weight: cw[dout][di][kk] -> [dout][k=kk*512+di] bf16 h/m/l
__global__ __launch_bounds__(256) void k_wsplit3_conv(const float* __restrict__ cw,
                                                      unsigned short* __restrict__ th,
                                                      unsigned short* __restrict__ tm,
                                                      unsigned short* __restrict__ tl) {
    int idx = blockIdx.x * 256 + threadIdx.x;
    if (idx >= DMODEL * 3 * DMODEL) return;
    int dout = idx / 1536, k = idx - dout * 1536;
    int kk = k >> 9, di = k & 511;
    unsigned short h, m, l;
    tsplit3(cw[(size_t)dout * 1536 + di * 3 + kk], h, m, l);
    th[idx] = h; tm[idx] = m; tl[idx] = l;
}

// ---------------- 6-term split-bf16 MFMA GEMM (fp32-grade: dropped terms <= fp32 ulp).
// Terms kept: hh, hm, mh, hl, lh, mm (dropped ml/lm ~2^-24, ll ~2^-32 rel).
// 128x128 tile, BK=32, 4 waves 2x2 (64x64, 4x4 f32x4 accs). LDS 6x8KB, swizzle
// seg^((row>>1)&3) on write+read. ACT: 0 none,1 GELU,2 relu.
template <int ACT, int CONV>
__global__ __launch_bounds__(256) void k_gemm6(const float* __restrict__ A, int lda,
                                               const unsigned short* __restrict__ B3h,
                                               const unsigned short* __restrict__ B3m,
                                               const unsigned short* __restrict__ B3l,
                                               const float* __restrict__ bias,
                                               float* __restrict__ C, int ldc,
                                               int K, int Tin, int Tout) {
    __shared__ __align__(16) unsigned short Ah[4096], Am[4096], Al[4096];
    __shared__ __align__(16) unsigned short Bh[4096], Bm[4096], Bl[4096];

    int tid = threadIdx.x;
    int lane = tid & 63, wave = tid >> 6;
    int lrow = lane & 15, lkg = lane >> 4;
    int wr = wave >> 1, wc = wave & 1;
    int wrbase = wr * 64, wcbase = wc * 64;
    int n0 = blockIdx.x * 128, m0 = blockIdx.y * 128;

    int sr[2], ss[2]; size_t abase[2], bbase[2]; int attv[2];
#pragma unroll
    for (int rd = 0; rd < 2; rd++) {
        int slot = tid + rd * 256;
        int row = slot >> 2, seg = slot & 3;
        sr[rd] = row; ss[rd] = seg;
        bbase[rd] = (size_t)(n0 + row) * K + seg * 8;
        int m = m0 + row;
        if (CONV) {
            int b = m / Tout, tt = m - b * Tout;
            abase[rd] = (size_t)b * Tin * DMODEL;
            attv[rd] = 2 * tt - 2;
        } else {
            abase[rd] = (size_t)m * lda + seg * 8;
            attv[rd] = 0;
        }
    }

    f32x4 acc[4][4];
#pragma unroll
    for (int mi = 0; mi < 4; mi++)
#pragma unroll
        for (int ni = 0; ni < 4; ni++) acc[mi][ni] = (f32x4){0.0f, 0.0f, 0.0f, 0.0f};

    for (int k0 = 0; k0 < K; k0 += 32) {
#pragma unroll
        for (int rd = 0; rd < 2; rd++) {
            int row = sr[rd], seg = ss[rd];
            int la = row * 32 + ((seg ^ ((row >> 1) & 3)) << 3);
            *(short8v*)(Bh + la) = *(const short8v*)(B3h + bbase[rd] + k0);
            *(short8v*)(Bm + la) = *(const short8v*)(B3m + bbase[rd] + k0);
            *(short8v*)(Bl + la) = *(const short8v*)(B3l + bbase[rd] + k0);
            const float* ap;
            if (CONV) {
                int f = attv[rd] + (k0 >> 9);
                if (f < 0) f = 0;
                ap = A + abase[rd] + (size_t)f * DMODEL + (k0 & 511) + seg * 8;
            } else {
                ap = A + abase[rd] + k0;
            }
            float4 v0 = *(const float4*)ap;
            float4 v1 = *(const float4*)(ap + 4);
            float vv[8] = {v0.x, v0.y, v0.z, v0.w, v1.x, v1.y, v1.z, v1.w};
            short8v hv, mv, lv;
#pragma unroll
            for (int j = 0; j < 8; j++) {
                unsigned short h, m, l;
                tsplit3(vv[j], h, m, l);
                hv[j] = (short)h; mv[j] = (short)m; lv[j] = (short)l;
            }
            *(short8v*)(Ah + la) = hv;
            *(short8v*)(Am + la) = mv;
            *(short8v*)(Al + la) = lv;
        }
        __syncthreads();

        short8v afh[4], afm[4], afl[4];
#pragma unroll
        for (int mi = 0; mi < 4; mi++) {
            int rowa = wrbase + mi * 16 + lrow;
            int off = rowa * 32 + ((lkg ^ ((rowa >> 1) & 3)) << 3);
            afh[mi] = *(const short8v*)(Ah + off);
            afm[mi] = *(const short8v*)(Am + off);
            afl[mi] = *(const short8v*)(Al + off);
        }
#pragma unroll
        for (int ni = 0; ni < 4; ni++) {
            int rowb = wcbase + ni * 16 + lrow;
            int off = rowb * 32 + ((lkg ^ ((rowb >> 1) & 3)) << 3);
            short8v bfh = *(const short8v*)(Bh + off);
            short8v bfm = *(const short8v*)(Bm + off);
            short8v bfl = *(const short8v*)(Bl + off);
#pragma unroll
            for (int mi = 0; mi < 4; mi++) {
                acc[mi][ni] = __builtin_amdgcn_mfma_f32_16x16x32_bf16(afh[mi], bfh, acc[mi][ni], 0, 0, 0);
                acc[mi][ni] = __builtin_amdgcn_mfma_f32_16x16x32_bf16(afh[mi], bfm, acc[mi][ni], 0, 0, 0);
                acc[mi][ni] = __builtin_amdgcn_mfma_f32_16x16x32_bf16(afm[mi], bfh, acc[mi][ni], 0, 0, 0);
                acc[mi][ni] = __builtin_amdgcn_mfma_f32_16x16x32_bf16(afh[mi], bfl, acc[mi][ni], 0, 0, 0);
                acc[mi][ni] = __builtin_amdgcn_mfma_f32_16x16x32_bf16(afl[mi], bfh, acc[mi][ni], 0, 0, 0);
                acc[mi][ni] = __builtin_amdgcn_mfma_f32_16x16x32_bf16(afm[mi], bfm, acc[mi][ni], 0, 0, 0);
            }
        }
        __syncthreads();
    }

    float bv[4];
#pragma unroll
    for (int ni = 0; ni < 4; ni++) bv[ni] = bias[n0 + wcbase + ni * 16 + lrow];
#pragma unroll
    for (int mi = 0; mi < 4; mi++)
#pragma unroll
        for (int ni = 0; ni < 4; ni++)
#pragma unroll
            for (int v = 0; v < 4; v++) {
                int row = m0 + wrbase + mi * 16 + lkg * 4 + v;
                int col = n0 + wcbase + ni * 16 + lrow;
                float x;
                if (ACT == 1) {
                    double dv = (double)acc[mi][ni][v] + (double)bv[ni];
                    dv = 0.5 * dv * (1.0 + erf(dv * 0.7071067811865476));
                    x = (float)dv;
                } else {
                    x = acc[mi][ni][v] + bv[ni];
                    if (ACT == 2) x = x > 0.0f ? x : 0.0f;
                }
                C[(size_t)row * ldc + col] = x;
            }
}

// ---------------- attention v3 (verified r7): swizzled K LDS, cooperative q, ILP PV.
__global__ __launch_bounds__(256) void k_attn(const float* q,
                                              const float* __restrict__ k,
                                              const float* __restrict__ v,
                                              float* out, int T) {
    __shared__ __align__(16) float Ks[98 * 128];     // swizzled, row stride 512B
    __shared__ __align__(16) float qsm[4][128];
    __shared__ float psm[4][128];
    int h = blockIdx.x, b = blockIdx.y;
    int tid = threadIdx.x;
    int lane = tid & 63;
    int wave = tid >> 6;
    size_t base = ((size_t)b * T) * DMODEL + (size_t)h * DHEAD;

    float4* Ks4 = (float4*)Ks;
    for (int it = tid; it < T * 32; it += 256) {
        int j = it >> 5, dq = it & 31;
        Ks4[j * 32 + (dq ^ (j & 7))] =
            *(const float4*)&k[base + (size_t)j * DMODEL + dq * 4];
    }
    __syncthreads();

    const float SCALE = 0.08838834764831845f;  // 1/sqrt(128)
    int niter = (T + 3) >> 2;
    for (int i0 = 0; i0 < niter; i0++) {
        int ibase = i0 * 4;
#pragma unroll
        for (int u = 0; u < 2; u++) {
            int idx = tid + u * 256;
            int r = idx >> 7, d = idx & 127;
            int grow = ibase + r;
            if (grow < T) qsm[r][d] = q[base + (size_t)grow * DMODEL + d];
        }
        __syncthreads();

        int i = ibase + wave;
        if (i < T) {
            int j1 = lane;
            int j2 = lane + 64;
            int j2c = j2 < T ? j2 : 0;
            bool a0 = (j1 <= i);
            bool a1 = (j2 <= i);
            const float4* kr1 = Ks4 + j1 * 32;
            const float4* kr2 = Ks4 + j2c * 32;
            const float4* qr = (const float4*)qsm[wave];
            int x1 = j1 & 7, x2 = j2c & 7;
            float4 s0 = {0.f, 0.f, 0.f, 0.f}, s1 = {0.f, 0.f, 0.f, 0.f};
#pragma unroll
            for (int dq = 0; dq < 32; dq++) {
                float4 qv = qr[dq];
                float4 k1 = kr1[dq ^ x1];
                float4 k2 = kr2[dq ^ x2];
                s0.x = fmaf(qv.x, k1.x, s0.x);
                s0.y = fmaf(qv.y, k1.y, s0.y);
                s0.z = fmaf(qv.z, k1.z, s0.z);
                s0.w = fmaf(qv.w, k1.w, s0.w);
                s1.x = fmaf(qv.x, k2.x, s1.x);
                s1.y = fmaf(qv.y, k2.y, s1.y);
                s1.z = fmaf(qv.z, k2.z, s1.z);
                s1.w = fmaf(qv.w, k2.w, s1.w);
            }
            float sv0 = a0 ? ((s0.x + s0.y) + (s0.z + s0.w)) * SCALE : -1e30f;
            float sv1 = a1 ? ((s1.x + s1.y) + (s1.z + s1.w)) * SCALE : -1e30f;

            float m = fmaxf(sv0, sv1);
#pragma unroll
            for (int off = 32; off > 0; off >>= 1) m = fmaxf(m, __shfl_xor(m, off, 64));
            float p0 = a0 ? expf(sv0 - m) : 0.0f;
            float p1 = a1 ? expf(sv1 - m) : 0.0f;
            float sum = p0 + p1;
#pragma unroll
            for (int off = 32; off > 0; off >>= 1) sum += __shfl_xor(sum, off, 64);
            float inv = 1.0f / sum;

            psm[wave][lane] = p0;
            psm[wave][lane + 64] = p1;

            float o0[4] = {0.f, 0.f, 0.f, 0.f}, o1[4] = {0.f, 0.f, 0.f, 0.f};
            const float* vb = v + base;
            for (int j = 0; j <= i; j += 4) {
#pragma unroll
                for (int u = 0; u < 4; u++) {
                    int jj = j + u;
                    float pj = psm[wave][jj];          // 0 beyond i
                    int jr = jj < T ? jj : T - 1;      // keep address in-bounds
                    const float* vr = vb + (size_t)jr * DMODEL;
                    o0[u] = fmaf(pj, vr[lane], o0[u]);
                    o1[u] = fmaf(pj, vr[lane + 64], o1[u]);
                }
            }
            out[base + (size_t)i * DMODEL + lane] =
                ((o0[0] + o0[1]) + (o0[2] + o0[3])) * inv;
            out[base + (size_t)i * DMODEL + lane + 64] =
                ((o1[0] + o1[1]) + (o1[2] + o1[3])) * inv;
        }
        __syncthreads();
    }
}

// ---------------- fused residual-add + LayerNorm
__global__ __launch_bounds__(128) void k_ln(const float* __restrict__ resid,
                                            const float* __restrict__ y,
                                            const float* __restrict__ g,
                                            const float* __restrict__ bta,
                                            float* __restrict__ out) {
    int row = blockIdx.x;
    int tid = threadIdx.x;
    size_t off = (size_t)row * DMODEL;
    double t[4];
#pragma unroll
    for (int i = 0; i < 4; i++) {
        int d = tid + i * 128;
        t[i] = (double)resid[off + d] + (double)y[off + d];
    }
    __shared__ double rd[2];
    double s = t[0] + t[1] + t[2] + t[3];
#pragma unroll
    for (int o = 32; o > 0; o >>= 1) s += __shfl_down(s, o, 64);
    if ((tid & 63) == 0) rd[tid >> 6] = s;
    __syncthreads();
    double mean = (rd[0] + rd[1]) * (1.0 / 512.0);
    double vs = 0.0;
#pragma unroll
    for (int i = 0; i < 4; i++) { double dl = t[i] - mean; vs += dl * dl; }
    __syncthreads();
#pragma unroll
    for (int o = 32; o > 0; o >>= 1) vs += __shfl_down(vs, o, 64);
    if ((tid & 63) == 0) rd[tid >> 6] = vs;
    __syncthreads();
    double var = (rd[0] + rd[1]) * (1.0 / 512.0);
    double scale = 1.0 / sqrt(var + 1e-5);
#pragma unroll
    for (int i = 0; i < 4; i++) {
        int d = tid + i * 128;
        out[off + d] = (float)((t[i] - mean) * scale * (double)g[d] + (double)bta[d]);
    }
}

// ---------------- codebook squared norms (fp64)
__global__ __launch_bounds__(64) void k_cbn(const float* __restrict__ cb,
                                            double* __restrict__ cbn) {
    int row = blockIdx.x;
    int tid = threadIdx.x;
    const float* r = cb + (size_t)row * DMODEL;
    double s = 0.0;
    for (int d = tid; d < DMODEL; d += 64) { double v = (double)r[d]; s = fma(v, v, s); }
#pragma unroll
    for (int o = 32; o > 0; o >>= 1) s += __shfl_down(s, o, 64);
    if (tid == 0) cbn[row] = s;
}

// ---------------- split fp32 -> (bf16 hi, bf16 lo residual), RNE (VQ path, verified)
__device__ __forceinline__ unsigned short f2bf(float f) {
    unsigned u = __float_as_uint(f);
    unsigned r = (u + 0x7fffu + ((u >> 16) & 1u)) >> 16;
    return (unsigned short)r;
}
__device__ __forceinline__ float bf2f(unsigned short h) {
    return __uint_as_float(((unsigned)h) << 16);
}

__global__ __launch_bounds__(256) void k_split(const float* __restrict__ in,
                                               unsigned short* __restrict__ hi,
                                               unsigned short* __restrict__ lo,
                                               int n4) {
    int i = blockIdx.x * 256 + threadIdx.x;
    if (i >= n4) return;
    float4 v = ((const float4*)in)[i];
    float vv[4] = {v.x, v.y, v.z, v.w};
    unsigned short h[4], l[4];
#pragma unroll
    for (int j = 0; j < 4; j++) {
        h[j] = f2bf(vv[j]);
        l[j] = f2bf(vv[j] - bf2f(h[j]));
    }
    ((ushort4*)hi)[i] = make_ushort4(h[0], h[1], h[2], h[3]);
    ((ushort4*)lo)[i] = make_ushort4(l[0], l[1], l[2], l[3]);
}

// ---------------- codebook transpose: cbT[d][c] = cb[c][d] (LDS-tiled, coalesced)
__global__ __launch_bounds__(256) void k_cbT(const float* __restrict__ cb,
                                             float* __restrict__ cbT) {
    __shared__ float t[64][65];
    int c0 = blockIdx.x * 64, d0 = blockIdx.y * 64;
    int tid = threadIdx.x;
#pragma unroll
    for (int i = 0; i < 16; i++) {
        int e = tid + i * 256;
        t[e >> 6][e & 63] = cb[(size_t)(c0 + (e >> 6)) * DMODEL + d0 + (e & 63)];
    }
    __syncthreads();
#pragma unroll
    for (int i = 0; i < 16; i++) {
        int e = tid + i * 256;
        int d = e >> 6, c = e & 63;
        cbT[(size_t)(d0 + d) * KCB + c0 + c] = t[c][d];
    }
}

// ---------------- VQ phase 1: split-bf16 MFMA GEMM, LDS-staged (verified r3/r5/r6/r7).
__global__ __launch_bounds__(256) void k_vq1m(const unsigned short* __restrict__ xh,
                                              const unsigned short* __restrict__ xl,
                                              const unsigned short* __restrict__ ch,
                                              const unsigned short* __restrict__ cl,
                                              const double* __restrict__ cbn,
                                              float4* __restrict__ cand) {
    __shared__ __align__(16) unsigned char smem[65536];
    unsigned short* AhU = (unsigned short*)smem;           // [128][64]
    unsigned short* AlU = AhU + 8192;
    unsigned short* BhU = AlU + 8192;
    unsigned short* BlU = BhU + 8192;

    int tid = threadIdx.x;
    int lane = tid & 63, wave = tid >> 6;
    int lrow = lane & 15;
    int lkg = lane >> 4;
    int wr = wave >> 1, wc = wave & 1;
    int wrbase = wr * 64, wcbase = wc * 64;

    int wg = (blockIdx.x & 7) * (6272 / 8) + (blockIdx.x >> 3);
    int bx = wg / 98;
    int by = wg % 98;
    int r0 = by * 128, c0 = bx * 128;

    const int srow = tid >> 3;
    const int seg = tid & 7;
    const int sw = seg ^ (srow & 7);

    f32x4 acc[4][4];
#pragma unroll
    for (int m = 0; m < 4; m++)
#pragma unroll
        for (int n = 0; n < 4; n++) acc[m][n] = (f32x4){0.0f, 0.0f, 0.0f, 0.0f};

    for (int ks = 0; ks < 8; ks++) {
        int k0 = ks * 64;
#pragma unroll
        for (int rd = 0; rd < 4; rd++) {
            int row = rd * 32 + srow;
            size_t ga = (((size_t)(r0 + row)) << 9) + k0 + seg * 8;
            size_t gb = (((size_t)(c0 + row)) << 9) + k0 + seg * 8;
            int la = row * 64 + sw * 8;
            *(short8v*)(AhU + la) = *(const short8v*)(xh + ga);
            *(short8v*)(AlU + la) = *(const short8v*)(xl + ga);
            *(short8v*)(BhU + la) = *(const short8v*)(ch + gb);
            *(short8v*)(BlU + la) = *(const short8v*)(cl + gb);
        }
        __syncthreads();
#pragma unroll
        for (int ksub = 0; ksub < 2; ksub++) {
            int segsw = ((ksub * 4 + lkg) ^ (lrow & 7)) * 8;
            short8v afh[4], afl[4], bfh[4], bfl[4];
#pragma unroll
            for (int m = 0; m < 4; m++) {
                int off = (wrbase + m * 16 + lrow) * 64 + segsw;
                afh[m] = *(const short8v*)(AhU + off);
                afl[m] = *(const short8v*)(AlU + off);
            }
#pragma unroll
            for (int n = 0; n < 4; n++) {
                int off = (wcbase + n * 16 + lrow) * 64 + segsw;
                bfh[n] = *(const short8v*)(BhU + off);
                bfl[n] = *(const short8v*)(BlU + off);
            }
#pragma unroll
            for (int m = 0; m < 4; m++)
#pragma unroll
                for (int n = 0; n < 4; n++) {
                    acc[m][n] = __builtin_amdgcn_mfma_f32_16x16x32_bf16(afh[m], bfh[n], acc[m][n], 0, 0, 0);
                    acc[m][n] = __builtin_amdgcn_mfma_f32_16x16x32_bf16(afh[m], bfl[n], acc[m][n], 0, 0, 0);
                    acc[m][n] = __builtin_amdgcn_mfma_f32_16x16x32_bf16(afl[m], bfh[n], acc[m][n], 0, 0, 0);
                }
        }
        __syncthreads();
    }

    float cnv[4];
#pragma unroll
    for (int n = 0; n < 4; n++) cnv[n] = (float)cbn[c0 + wcbase + n * 16 + lrow];

    float* sD = (float*)smem;
    int* sI = (int*)(smem + 32768);
#pragma unroll
    for (int m = 0; m < 4; m++)
#pragma unroll
        for (int v = 0; v < 4; v++) {
            int row = wrbase + m * 16 + lkg * 4 + v;
            float d1 = 1e30f, d2 = 1e30f; int j1 = 0, j2 = 0;
#pragma unroll
            for (int n = 0; n < 4; n++) {
                int code = c0 + wcbase + n * 16 + lrow;
                float d = cnv[n] - 2.0f * acc[m][n][v];
                if (d < d1 || (d == d1 && code < j1)) { d2 = d1; j2 = j1; d1 = d; j1 = code; }
                else if (d < d2 || (d == d2 && code < j2)) { d2 = d; j2 = code; }
            }
            int slot = (wc * 16 + lrow) * 2;
            sD[row * 64 + slot] = d1; sD[row * 64 + slot + 1] = d2;
            sI[row * 64 + slot] = j1; sI[row * 64 + slot + 1] = j2;
        }
    __syncthreads();
    if (tid < 128) {
        float d1 = 1e30f, d2 = 1e30f; int j1 = 0, j2 = 0;
        for (int e = 0; e < 64; e++) {
            float d = sD[tid * 64 + e]; int ix = sI[tid * 64 + e];
            if (d < d1 || (d == d1 && ix < j1)) { d2 = d1; j2 = j1; d1 = d; j1 = ix; }
            else if (d < d2 || (d == d2 && ix < j2)) { d2 = d; j2 = ix; }
        }
        cand[(size_t)bx * NROWS + r0 + tid] =
            make_float4(d1, __int_as_float(j1), d2, __int_as_float(j2));
    }
}

// ---------------- VQ phase 2: merge 64 splits' top-2; flag near-ties; compact list
__global__ __launch_bounds__(256) void k_vq2(const float4* __restrict__ cand,
                                             int* __restrict__ idxbuf,
                                             int* __restrict__ flagbuf,
                                             int* __restrict__ flaglist,
                                             int* __restrict__ nflag, int nrows) {
    int row = blockIdx.x * 256 + threadIdx.x;
    if (row >= nrows) return;
    float d1 = 1e30f, d2 = 1e30f; int j1 = 0, j2 = 0;
    for (int s = 0; s < NSPLIT; s++) {
        float4 c = cand[(size_t)s * nrows + row];
        float dd[2] = {c.x, c.z};
        int ii[2] = {__float_as_int(c.y), __float_as_int(c.w)};
#pragma unroll
        for (int e = 0; e < 2; e++) {
            float d = dd[e]; int ix = ii[e];
            if (d < d1 || (d == d1 && ix < j1)) { d2 = d1; j2 = j1; d1 = d; j1 = ix; }
            else if (d < d2 || (d == d2 && ix < j2)) { d2 = d; j2 = ix; }
        }
    }
    idxbuf[row] = j1;
    int f = (d2 - d1 < VEPS) ? 1 : 0;
    flagbuf[row] = f;
    if (f) {
        int pos = atomicAdd(nflag, 1);
        flaglist[pos] = row;
    }
}

// ---------------- VQ phase 3a: flagged rows x 32 code-slabs; exact fp64 per slab.
// Grid (256, 32): block scans 256 codes via cbT (coalesced lane-consecutive codes).
__global__ __launch_bounds__(256) void k_vq3a(const float* __restrict__ x,
                                              const float* __restrict__ cbT,
                                              const double* __restrict__ cbn,
                                              const int* __restrict__ flaglist,
                                              const int* __restrict__ nflag,
                                              double* __restrict__ partd,
                                              int* __restrict__ parti) {
    __shared__ __align__(16) float xs[DMODEL];
    __shared__ double sd[256];
    __shared__ int si[256];
    int nf = *nflag;
    int slab = blockIdx.y;
    int tid = threadIdx.x;
    for (int fi = blockIdx.x; fi < nf; fi += gridDim.x) {
        int row = flaglist[fi];
        xs[tid] = x[(size_t)row * DMODEL + tid];
        xs[tid + 256] = x[(size_t)row * DMODEL + tid + 256];
        __syncthreads();
        int c = slab * 256 + tid;
        double a0 = 0.0, a1 = 0.0, a2 = 0.0, a3 = 0.0;
        const float4* xs4 = (const float4*)xs;
#pragma unroll 8
        for (int q = 0; q < DMODEL / 4; q++) {
            float4 xv = xs4[q];
            const float* cp = cbT + (size_t)(q * 4) * KCB + c;
            a0 = fma((double)xv.x, (double)cp[0], a0);
            a1 = fma((double)xv.y, (double)cp[KCB], a1);
            a2 = fma((double)xv.z, (double)cp[2 * KCB], a2);
            a3 = fma((double)xv.w, (double)cp[3 * KCB], a3);
        }
        sd[tid] = cbn[c] - 2.0 * ((a0 + a1) + (a2 + a3));
        si[tid] = c;
        __syncthreads();
        for (int off = 128; off > 0; off >>= 1) {
            if (tid < off) {
                if (sd[tid + off] < sd[tid] ||
                    (sd[tid + off] == sd[tid] && si[tid + off] < si[tid])) {
                    sd[tid] = sd[tid + off]; si[tid] = si[tid + off];
                }
            }
            __syncthreads();
        }
        if (tid == 0) {
            partd[(size_t)row * 32 + slab] = sd[0];
            parti[(size_t)row * 32 + slab] = si[0];
        }
        __syncthreads();
    }
}

// ---------------- VQ phase 3b: merge 32 slab partials per flagged row; write outputs
__global__ __launch_bounds__(256) void k_vq3b(const float* __restrict__ cb,
                                              const int* __restrict__ idxbuf,
                                              const int* __restrict__ flagbuf,
                                              const double* __restrict__ partd,
                                              const int* __restrict__ parti,
                                              float* __restrict__ outq,
                                              float* __restrict__ outi) {
    int row = blockIdx.x;
    int tid = threadIdx.x;
    __shared__ int bestsh;
    int best = idxbuf[row];
    if (flagbuf[row]) {
        if (tid == 0) {
            double bd = partd[(size_t)row * 32];
            int bi = parti[(size_t)row * 32];
            for (int s = 1; s < 32; s++) {
                double d = partd[(size_t)row * 32 + s];
                int ix = parti[(size_t)row * 32 + s];
                if (d < bd || (d == bd && ix < bi)) { bd = d; bi = ix; }
            }
            bestsh = bi;
        }
        __syncthreads();
        best = bestsh;
    }
    const float* crow = cb + (size_t)best * DMODEL;
    outq[(size_t)row * DMODEL + tid] = crow[tid];
    outq[(size_t)row * DMODEL + tid + 256] = crow[tid + 256];
    if (tid == 0) outi[row] = (float)best;
}

extern "C" void kernel_launch(void* const* d_in, const int* in_sizes, int n_in,
                              void* d_out, int out_size, void* d_ws, size_t ws_size,
                              hipStream_t stream) {
    const float* motion = (const float*)d_in[0];
    const float* conv_w = (const float*)d_in[1];
    const float* conv_b = (const float*)d_in[2];
    const float* wqkv   = (const float*)d_in[3];
    const float* bqkv   = (const float*)d_in[4];
    const float* wo     = (const float*)d_in[5];
    const float* bo     = (const float*)d_in[6];
    const float* ln1g   = (const float*)d_in[7];
    const float* ln1b   = (const float*)d_in[8];
    const float* ln2g   = (const float*)d_in[9];
    const float* ln2b   = (const float*)d_in[10];
    const float* w1     = (const float*)d_in[11];
    const float* b1     = (const float*)d_in[12];
    const float* w2     = (const float*)d_in[13];
    const float* b2     = (const float*)d_in[14];
    const float* cb     = (const float*)d_in[15];

    const size_t SZc = (size_t)25088 * DMODEL;
    float* wsf = (float*)d_ws;
    float*  S0  = wsf + 0 * SZc;
    float*  S1  = wsf + 1 * SZc;
    float*  S2  = wsf + 2 * SZc;
    float*  S3  = wsf + 3 * SZc;
    char* p = (char*)(wsf + 4 * SZc);
    unsigned short* wh = (unsigned short*)p;   p += (size_t)786432 * 2;
    unsigned short* wm = (unsigned short*)p;   p += (size_t)786432 * 2;
    unsigned short* wl = (unsigned short*)p;   p += (size_t)786432 * 2;
    double* cbn    = (double*)p;               p += KCB * 8;
    int*   idxbuf  = (int*)p;                  p += NROWS * 4;
    int*   flagbuf = (int*)p;                  p += NROWS * 4;
    int*   flaglist= (int*)p;                  p += NROWS * 4;
    int*   nflag   = (int*)p;                  p += 256;
    double* partd  = (double*)p;               p += (size_t)NROWS * 32 * 8;
    int*   parti   = (int*)p;                  p += (size_t)NROWS * 32 * 4;

    k_cbn<<<dim3(KCB), dim3(64), 0, stream>>>(cb, cbn);

    const float* xin = motion;
    int Tin = 196;
    for (int l = 0; l < 2; l++) {
        int Tout = Tin / 2;            // 98, then 49
        int M = BBATCH * Tout;         // 25088, then 12544
        const float* wq = wqkv + (size_t)l * DMODEL * 3 * DMODEL;
        const float* bq = bqkv + (size_t)l * 3 * DMODEL;

        // conv (fused gather + exact fp64 GELU epilogue)
        k_wsplit3_conv<<<dim3(3072), dim3(256), 0, stream>>>(
            conv_w + (size_t)l * DMODEL * DMODEL * 3, wh, wm, wl);
        k_gemm6<1, 1><<<dim3(4, M / 128), dim3(256), 0, stream>>>(
            xin, DMODEL, wh, wm, wl, conv_b + l * DMODEL, S0, DMODEL,
            3 * DMODEL, Tin, Tout);
        // qkv
        float* qkvdst[3] = {S1, S2, S3};
        for (int s = 0; s < 3; s++) {
            k_wsplit3T<<<dim3(1024), dim3(256), 0, stream>>>(
                wq + s * DMODEL, 3 * DMODEL, DMODEL, DMODEL * DMODEL, wh, wm, wl);
            k_gemm6<0, 0><<<dim3(4, M / 128), dim3(256), 0, stream>>>(
                S0, DMODEL, wh, wm, wl, bq + s * DMODEL, qkvdst[s], DMODEL,
                DMODEL, 1, 1);
        }
        k_attn<<<dim3(NHEAD, BBATCH), dim3(256), 0, stream>>>(S1, S2, S3, S1, Tout);
        // wo
        k_wsplit3T<<<dim3(1024), dim3(256), 0, stream>>>(
            wo + (size_t)l * DMODEL * DMODEL, DMODEL, DMODEL, DMODEL * DMODEL, wh, wm, wl);
        k_gemm6<0, 0><<<dim3(4, M / 128), dim3(256), 0, stream>>>(
            S1, DMODEL, wh, wm, wl, bo + l * DMODEL, S2, DMODEL, DMODEL, 1, 1);
        k_ln<<<dim3(M), dim3(128), 0, stream>>>(S0, S2, ln1g + l * DMODEL, ln1b + l * DMODEL, S3);
        // ffn
        k_wsplit3T<<<dim3(2048), dim3(256), 0, stream>>>(
            w1 + (size_t)l * DMODEL * DFFN, DFFN, DMODEL, DMODEL * DFFN, wh, wm, wl);
        k_gemm6<2, 0><<<dim3(8, M / 128), dim3(256), 0, stream>>>(
            S3, DMODEL, wh, wm, wl, b1 + l * DFFN, S1, DFFN, DMODEL, 1, 1);
        k_wsplit3T<<<dim3(2048), dim3(256), 0, stream>>>(
            w2 + (size_t)l * DFFN * DMODEL, DMODEL, DFFN, DMODEL * DFFN, wh, wm, wl);
        k_gemm6<0, 0><<<dim3(4, M / 128), dim3(256), 0, stream>>>(
            S1, DFFN, wh, wm, wl, b2 + l * DMODEL, S0, DMODEL, DFFN, 1, 1);
        k_ln<<<dim3(M), dim3(128), 0, stream>>>(S3, S0, ln2g + l * DMODEL, ln2b + l * DMODEL, S1);

        xin = S1;
        Tin = Tout;
    }

    // ---- VQ: split x (S1) and codebook to bf16 hi/lo in freed scratch (S2, S3).
    // cand (64 splits x NROWS float4 = 12.85 MB) lives in freed S0.
    unsigned short* xh = (unsigned short*)S2;
    unsigned short* xl = xh + (size_t)NROWS * DMODEL;
    unsigned short* chb = (unsigned short*)S3;
    unsigned short* clb = chb + (size_t)KCB * DMODEL;
    float4* cand = (float4*)S0;
    k_split<<<dim3(NROWS * DMODEL / 4 / 256), dim3(256), 0, stream>>>(S1, xh, xl,
                                                                      NROWS * DMODEL / 4);
    k_split<<<dim3(KCB * DMODEL / 4 / 256), dim3(256), 0, stream>>>(cb, chb, clb,
                                                                    KCB * DMODEL / 4);

    float* outq = (float*)d_out;
    float* outi = outq + (size_t)NROWS * DMODEL;
    hipMemsetAsync(nflag, 0, sizeof(int), stream);
    k_vq1m<<<dim3(98 * NSPLIT), dim3(256), 0, stream>>>(xh, xl, chb, clb, cbn, cand);
    k_vq2<<<dim3(49), dim3(256), 0, stream>>>(cand, idxbuf, flagbuf, flaglist, nflag, NROWS);
    // cbT overwrites chb/clb region (dead after vq1m) — stream order guarantees safety
    float* cbT = (float*)S3;
    k_cbT<<<dim3(KCB / 64, DMODEL / 64), dim3(256), 0, stream>>>(cb, cbT);
    k_vq3a<<<dim3(256, 32), dim3(256), 0, stream>>>(S1, cbT, cbn, flaglist, nflag,
                                                    partd, parti);
    k_vq3b<<<dim3(NROWS), dim3(256), 0, stream>>>(cb, idxbuf, flagbuf, partd, parti,
                                                  outq, outi);
}

// Round 10
// 2558.688 us; speedup vs baseline: 2.1579x; 1.0544x over previous
//
#include <hip/hip_runtime.h>
#include <hip/hip_bf16.h>
#include <math.h>

#define BBATCH 256
#define DMODEL 512
#define NHEAD 4
#define DHEAD 128
#define DFFN 1024
#define KCB 8192
#define VEPS 0.02f
#define NROWS 12544
#define NSPLIT 64   // 8192 / 128 code tiles

typedef __attribute__((ext_vector_type(8))) short short8v;   // 8 bf16 in 4 VGPRs
typedef __attribute__((ext_vector_type(4))) float f32x4;

// ---------------- exact 3-way truncation split: x == hi + mid + lo (24 mantissa bits)
__device__ __forceinline__ void tsplit3(float x, unsigned short& h,
                                        unsigned short& m, unsigned short& l) {
    unsigned u = __float_as_uint(x);
    float hf = __uint_as_float(u & 0xffff0000u);
    float r = x - hf;                       // exact
    unsigned ru = __float_as_uint(r);
    float mf = __uint_as_float(ru & 0xffff0000u);
    float r2 = r - mf;                      // exact
    h = (unsigned short)(u >> 16);
    m = (unsigned short)(ru >> 16);
    l = (unsigned short)(__float_as_uint(r2) >> 16);
}

// ---------------- weight transpose + 3-way split, LDS-tiled (coalesced both sides).
// W[K][N] row-major (ld=ldw) -> th/tm/tl[N][K]. Grid (K/64, N/64), 256 thr.
__global__ __launch_bounds__(256) void k_wsplit3Tt(const float* __restrict__ W, int ldw,
                                                   int K,
                                                   unsigned short* __restrict__ th,
                                                   unsigned short* __restrict__ tm,
                                                   unsigned short* __restrict__ tl) {
    __shared__ float t[64][65];
    int k0 = blockIdx.x * 64, n0 = blockIdx.y * 64;
    int tid = threadIdx.x;
#pragma unroll
    for (int i = 0; i < 16; i++) {
        int e = tid + i * 256;
        int r = e >> 6, c = e & 63;
        t[r][c] = W[(size_t)(k0 + r) * ldw + n0 + c];
    }
    __syncthreads();
#pragma unroll
    for (int i = 0; i < 16; i++) {
        int e = tid + i * 256;
        int rr = e >> 6, cc = e & 63;          // rr: n-local, cc: k-local
        unsigned short h, m, l;
        tsplit3(t[cc][rr], h, m, l);
        size_t o = (size_t)(n0 + rr) * K + k0 + cc;
        th[o] = h; tm[o] = m; tl[o] = l;
    }
}

// ---------------- conv weight: cw[dout][di][kk] -> [dout][k=kk*512+di] bf16 h/m/l
__global__ __launch_bounds__(256) void k_wsplit3_conv(const float* __restrict__ cw,
                                                      unsigned short* __restrict__ th,
                                                      unsigned short* __restrict__ tm,
                                                      unsigned short* __restrict__ tl) {
    int idx = blockIdx.x * 256 + threadIdx.x;
    if (idx >= DMODEL * 3 * DMODEL) return;
    int dout = idx / 1536, k = idx - dout * 1536;
    int kk = k >> 9, di = k & 511;
    unsigned short h, m, l;
    tsplit3(cw[(size_t)dout * 1536 + di * 3 + kk], h, m, l);
    th[idx] = h; tm[idx] = m; tl[idx] = l;
}

// ---------------- 6-term split-bf16 MFMA GEMM (fp32-grade; verified r8).
// XCD chunked swizzle: blocks sharing an A-tile co-locate on one XCD's L2.
template <int ACT, int CONV>
__global__ __launch_bounds__(256) void k_gemm6(const float* __restrict__ A, int lda,
                                               const unsigned short* __restrict__ B3h,
                                               const unsigned short* __restrict__ B3m,
                                               const unsigned short* __restrict__ B3l,
                                               const float* __restrict__ bias,
                                               float* __restrict__ C, int ldc,
                                               int K, int Tin, int Tout) {
    __shared__ __align__(16) unsigned short Ah[4096], Am[4096], Al[4096];
    __shared__ __align__(16) unsigned short Bh[4096], Bm[4096], Bl[4096];

    int tid = threadIdx.x;
    int lane = tid & 63, wave = tid >> 6;
    int lrow = lane & 15, lkg = lane >> 4;
    int wr = wave >> 1, wc = wave & 1;
    int wrbase = wr * 64, wcbase = wc * 64;

    // bijective chunked XCD swizzle (all grids have nwg % 8 == 0)
    int nbx = gridDim.x;
    int nwg = nbx * gridDim.y;
    int orig = blockIdx.y * nbx + blockIdx.x;
    int newid = (orig & 7) * (nwg >> 3) + (orig >> 3);
    int n0 = (newid % nbx) * 128, m0 = (newid / nbx) * 128;

    int sr[2], ss[2]; size_t abase[2], bbase[2]; int attv[2];
#pragma unroll
    for (int rd = 0; rd < 2; rd++) {
        int slot = tid + rd * 256;
        int row = slot >> 2, seg = slot & 3;
        sr[rd] = row; ss[rd] = seg;
        bbase[rd] = (size_t)(n0 + row) * K + seg * 8;
        int m = m0 + row;
        if (CONV) {
            int b = m / Tout, tt = m - b * Tout;
            abase[rd] = (size_t)b * Tin * DMODEL;
            attv[rd] = 2 * tt - 2;
        } else {
            abase[rd] = (size_t)m * lda + seg * 8;
            attv[rd] = 0;
        }
    }

    f32x4 acc[4][4];
#pragma unroll
    for (int mi = 0; mi < 4; mi++)
#pragma unroll
        for (int ni = 0; ni < 4; ni++) acc[mi][ni] = (f32x4){0.0f, 0.0f, 0.0f, 0.0f};

    for (int k0 = 0; k0 < K; k0 += 32) {
#pragma unroll
        for (int rd = 0; rd < 2; rd++) {
            int row = sr[rd], seg = ss[rd];
            int la = row * 32 + ((seg ^ ((row >> 1) & 3)) << 3);
            *(short8v*)(Bh + la) = *(const short8v*)(B3h + bbase[rd] + k0);
            *(short8v*)(Bm + la) = *(const short8v*)(B3m + bbase[rd] + k0);
            *(short8v*)(Bl + la) = *(const short8v*)(B3l + bbase[rd] + k0);
            const float* ap;
            if (CONV) {
                int f = attv[rd] + (k0 >> 9);
                if (f < 0) f = 0;
                ap = A + abase[rd] + (size_t)f * DMODEL + (k0 & 511) + seg * 8;
            } else {
                ap = A + abase[rd] + k0;
            }
            float4 v0 = *(const float4*)ap;
            float4 v1 = *(const float4*)(ap + 4);
            float vv[8] = {v0.x, v0.y, v0.z, v0.w, v1.x, v1.y, v1.z, v1.w};
            short8v hv, mv, lv;
#pragma unroll
            for (int j = 0; j < 8; j++) {
                unsigned short h, m, l;
                tsplit3(vv[j], h, m, l);
                hv[j] = (short)h; mv[j] = (short)m; lv[j] = (short)l;
            }
            *(short8v*)(Ah + la) = hv;
            *(short8v*)(Am + la) = mv;
            *(short8v*)(Al + la) = lv;
        }
        __syncthreads();

        short8v afh[4], afm[4], afl[4];
#pragma unroll
        for (int mi = 0; mi < 4; mi++) {
            int rowa = wrbase + mi * 16 + lrow;
            int off = rowa * 32 + ((lkg ^ ((rowa >> 1) & 3)) << 3);
            afh[mi] = *(const short8v*)(Ah + off);
            afm[mi] = *(const short8v*)(Am + off);
            afl[mi] = *(const short8v*)(Al + off);
        }
#pragma unroll
        for (int ni = 0; ni < 4; ni++) {
            int rowb = wcbase + ni * 16 + lrow;
            int off = rowb * 32 + ((lkg ^ ((rowb >> 1) & 3)) << 3);
            short8v bfh = *(const short8v*)(Bh + off);
            short8v bfm = *(const short8v*)(Bm + off);
            short8v bfl = *(const short8v*)(Bl + off);
#pragma unroll
            for (int mi = 0; mi < 4; mi++) {
                acc[mi][ni] = __builtin_amdgcn_mfma_f32_16x16x32_bf16(afh[mi], bfh, acc[mi][ni], 0, 0, 0);
                acc[mi][ni] = __builtin_amdgcn_mfma_f32_16x16x32_bf16(afh[mi], bfm, acc[mi][ni], 0, 0, 0);
                acc[mi][ni] = __builtin_amdgcn_mfma_f32_16x16x32_bf16(afm[mi], bfh, acc[mi][ni], 0, 0, 0);
                acc[mi][ni] = __builtin_amdgcn_mfma_f32_16x16x32_bf16(afh[mi], bfl, acc[mi][ni], 0, 0, 0);
                acc[mi][ni] = __builtin_amdgcn_mfma_f32_16x16x32_bf16(afl[mi], bfh, acc[mi][ni], 0, 0, 0);
                acc[mi][ni] = __builtin_amdgcn_mfma_f32_16x16x32_bf16(afm[mi], bfm, acc[mi][ni], 0, 0, 0);
            }
        }
        __syncthreads();
    }

    float bv[4];
#pragma unroll
    for (int ni = 0; ni < 4; ni++) bv[ni] = bias[n0 + wcbase + ni * 16 + lrow];
#pragma unroll
    for (int mi = 0; mi < 4; mi++)
#pragma unroll
        for (int ni = 0; ni < 4; ni++)
#pragma unroll
            for (int v = 0; v < 4; v++) {
                int row = m0 + wrbase + mi * 16 + lkg * 4 + v;
                int col = n0 + wcbase + ni * 16 + lrow;
                float x;
                if (ACT == 1) {
                    double dv = (double)acc[mi][ni][v] + (double)bv[ni];
                    dv = 0.5 * dv * (1.0 + erf(dv * 0.7071067811865476));
                    x = (float)dv;
                } else {
                    x = acc[mi][ni][v] + bv[ni];
                    if (ACT == 2) x = x > 0.0f ? x : 0.0f;
                }
                C[(size_t)row * ldc + col] = x;
            }
}

// ---------------- attention v3 (verified r7): swizzled K LDS, cooperative q, ILP PV.
__global__ __launch_bounds__(256) void k_attn(const float* q,
                                              const float* __restrict__ k,
                                              const float* __restrict__ v,
                                              float* out, int T) {
    __shared__ __align__(16) float Ks[98 * 128];     // swizzled, row stride 512B
    __shared__ __align__(16) float qsm[4][128];
    __shared__ float psm[4][128];
    int h = blockIdx.x, b = blockIdx.y;
    int tid = threadIdx.x;
    int lane = tid & 63;
    int wave = tid >> 6;
    size_t base = ((size_t)b * T) * DMODEL + (size_t)h * DHEAD;

    float4* Ks4 = (float4*)Ks;
    for (int it = tid; it < T * 32; it += 256) {
        int j = it >> 5, dq = it & 31;
        Ks4[j * 32 + (dq ^ (j & 7))] =
            *(const float4*)&k[base + (size_t)j * DMODEL + dq * 4];
    }
    __syncthreads();

    const float SCALE = 0.08838834764831845f;  // 1/sqrt(128)
    int niter = (T + 3) >> 2;
    for (int i0 = 0; i0 < niter; i0++) {
        int ibase = i0 * 4;
#pragma unroll
        for (int u = 0; u < 2; u++) {
            int idx = tid + u * 256;
            int r = idx >> 7, d = idx & 127;
            int grow = ibase + r;
            if (grow < T) qsm[r][d] = q[base + (size_t)grow * DMODEL + d];
        }
        __syncthreads();

        int i = ibase + wave;
        if (i < T) {
            int j1 = lane;
            int j2 = lane + 64;
            int j2c = j2 < T ? j2 : 0;
            bool a0 = (j1 <= i);
            bool a1 = (j2 <= i);
            const float4* kr1 = Ks4 + j1 * 32;
            const float4* kr2 = Ks4 + j2c * 32;
            const float4* qr = (const float4*)qsm[wave];
            int x1 = j1 & 7, x2 = j2c & 7;
            float4 s0 = {0.f, 0.f, 0.f, 0.f}, s1 = {0.f, 0.f, 0.f, 0.f};
#pragma unroll
            for (int dq = 0; dq < 32; dq++) {
                float4 qv = qr[dq];
                float4 k1 = kr1[dq ^ x1];
                float4 k2 = kr2[dq ^ x2];
                s0.x = fmaf(qv.x, k1.x, s0.x);
                s0.y = fmaf(qv.y, k1.y, s0.y);
                s0.z = fmaf(qv.z, k1.z, s0.z);
                s0.w = fmaf(qv.w, k1.w, s0.w);
                s1.x = fmaf(qv.x, k2.x, s1.x);
                s1.y = fmaf(qv.y, k2.y, s1.y);
                s1.z = fmaf(qv.z, k2.z, s1.z);
                s1.w = fmaf(qv.w, k2.w, s1.w);
            }
            float sv0 = a0 ? ((s0.x + s0.y) + (s0.z + s0.w)) * SCALE : -1e30f;
            float sv1 = a1 ? ((s1.x + s1.y) + (s1.z + s1.w)) * SCALE : -1e30f;

            float m = fmaxf(sv0, sv1);
#pragma unroll
            for (int off = 32; off > 0; off >>= 1) m = fmaxf(m, __shfl_xor(m, off, 64));
            float p0 = a0 ? expf(sv0 - m) : 0.0f;
            float p1 = a1 ? expf(sv1 - m) : 0.0f;
            float sum = p0 + p1;
#pragma unroll
            for (int off = 32; off > 0; off >>= 1) sum += __shfl_xor(sum, off, 64);
            float inv = 1.0f / sum;

            psm[wave][lane] = p0;
            psm[wave][lane + 64] = p1;

            float o0[4] = {0.f, 0.f, 0.f, 0.f}, o1[4] = {0.f, 0.f, 0.f, 0.f};
            const float* vb = v + base;
            for (int j = 0; j <= i; j += 4) {
#pragma unroll
                for (int u = 0; u < 4; u++) {
                    int jj = j + u;
                    float pj = psm[wave][jj];          // 0 beyond i
                    int jr = jj < T ? jj : T - 1;      // keep address in-bounds
                    const float* vr = vb + (size_t)jr * DMODEL;
                    o0[u] = fmaf(pj, vr[lane], o0[u]);
                    o1[u] = fmaf(pj, vr[lane + 64], o1[u]);
                }
            }
            out[base + (size_t)i * DMODEL + lane] =
                ((o0[0] + o0[1]) + (o0[2] + o0[3])) * inv;
            out[base + (size_t)i * DMODEL + lane + 64] =
                ((o1[0] + o1[1]) + (o1[2] + o1[3])) * inv;
        }
        __syncthreads();
    }
}

// ---------------- fused residual-add + LayerNorm
__global__ __launch_bounds__(128) void k_ln(const float* __restrict__ resid,
                                            const float* __restrict__ y,
                                            const float* __restrict__ g,
                                            const float* __restrict__ bta,
                                            float* __restrict__ out) {
    int row = blockIdx.x;
    int tid = threadIdx.x;
    size_t off = (size_t)row * DMODEL;
    double t[4];
#pragma unroll
    for (int i = 0; i < 4; i++) {
        int d = tid + i * 128;
        t[i] = (double)resid[off + d] + (double)y[off + d];
    }
    __shared__ double rd[2];
    double s = t[0] + t[1] + t[2] + t[3];
#pragma unroll
    for (int o = 32; o > 0; o >>= 1) s += __shfl_down(s, o, 64);
    if ((tid & 63) == 0) rd[tid >> 6] = s;
    __syncthreads();
    double mean = (rd[0] + rd[1]) * (1.0 / 512.0);
    double vs = 0.0;
#pragma unroll
    for (int i = 0; i < 4; i++) { double dl = t[i] - mean; vs += dl * dl; }
    __syncthreads();
#pragma unroll
    for (int o = 32; o > 0; o >>= 1) vs += __shfl_down(vs, o, 64);
    if ((tid & 63) == 0) rd[tid >> 6] = vs;
    __syncthreads();
    double var = (rd[0] + rd[1]) * (1.0 / 512.0);
    double scale = 1.0 / sqrt(var + 1e-5);
#pragma unroll
    for (int i = 0; i < 4; i++) {
        int d = tid + i * 128;
        out[off + d] = (float)((t[i] - mean) * scale * (double)g[d] + (double)bta[d]);
    }
}

// ---------------- codebook squared norms (fp64)
__global__ __launch_bounds__(64) void k_cbn(const float* __restrict__ cb,
                                            double* __restrict__ cbn) {
    int row = blockIdx.x;
    int tid = threadIdx.x;
    const float* r = cb + (size_t)row * DMODEL;
    double s = 0.0;
    for (int d = tid; d < DMODEL; d += 64) { double v = (double)r[d]; s = fma(v, v, s); }
#pragma unroll
    for (int o = 32; o > 0; o >>= 1) s += __shfl_down(s, o, 64);
    if (tid == 0) cbn[row] = s;
}

// ---------------- split fp32 -> (bf16 hi, bf16 lo residual), RNE (VQ path, verified)
__device__ __forceinline__ unsigned short f2bf(float f) {
    unsigned u = __float_as_uint(f);
    unsigned r = (u + 0x7fffu + ((u >> 16) & 1u)) >> 16;
    return (unsigned short)r;
}
__device__ __forceinline__ float bf2f(unsigned short h) {
    return __uint_as_float(((unsigned)h) << 16);
}

__global__ __launch_bounds__(256) void k_split(const float* __restrict__ in,
                                               unsigned short* __restrict__ hi,
                                               unsigned short* __restrict__ lo,
                                               int n4) {
    int i = blockIdx.x * 256 + threadIdx.x;
    if (i >= n4) return;
    float4 v = ((const float4*)in)[i];
    float vv[4] = {v.x, v.y, v.z, v.w};
    unsigned short h[4], l[4];
#pragma unroll
    for (int j = 0; j < 4; j++) {
        h[j] = f2bf(vv[j]);
        l[j] = f2bf(vv[j] - bf2f(h[j]));
    }
    ((ushort4*)hi)[i] = make_ushort4(h[0], h[1], h[2], h[3]);
    ((ushort4*)lo)[i] = make_ushort4(l[0], l[1], l[2], l[3]);
}

// ---------------- codebook transpose: cbT[d][c] = cb[c][d] (LDS-tiled, coalesced)
__global__ __launch_bounds__(256) void k_cbT(const float* __restrict__ cb,
                                             float* __restrict__ cbT) {
    __shared__ float t[64][65];
    int c0 = blockIdx.x * 64, d0 = blockIdx.y * 64;
    int tid = threadIdx.x;
#pragma unroll
    for (int i = 0; i < 16; i++) {
        int e = tid + i * 256;
        t[e >> 6][e & 63] = cb[(size_t)(c0 + (e >> 6)) * DMODEL + d0 + (e & 63)];
    }
    __syncthreads();
#pragma unroll
    for (int i = 0; i < 16; i++) {
        int e = tid + i * 256;
        int d = e >> 6, c = e & 63;
        cbT[(size_t)(d0 + d) * KCB + c0 + c] = t[c][d];
    }
}

// ---------------- VQ phase 1: split-bf16 MFMA GEMM, LDS-staged (verified r3..r8).
// Epilogue merge scan rotated: s=(e+tid)&63 -> banks (e+tid)&31, conflict-free.
__global__ __launch_bounds__(256) void k_vq1m(const unsigned short* __restrict__ xh,
                                              const unsigned short* __restrict__ xl,
                                              const unsigned short* __restrict__ ch,
                                              const unsigned short* __restrict__ cl,
                                              const double* __restrict__ cbn,
                                              float4* __restrict__ cand) {
    __shared__ __align__(16) unsigned char smem[65536];
    unsigned short* AhU = (unsigned short*)smem;           // [128][64]
    unsigned short* AlU = AhU + 8192;
    unsigned short* BhU = AlU + 8192;
    unsigned short* BlU = BhU + 8192;

    int tid = threadIdx.x;
    int lane = tid & 63, wave = tid >> 6;
    int lrow = lane & 15;
    int lkg = lane >> 4;
    int wr = wave >> 1, wc = wave & 1;
    int wrbase = wr * 64, wcbase = wc * 64;

    int wg = (blockIdx.x & 7) * (6272 / 8) + (blockIdx.x >> 3);
    int bx = wg / 98;
    int by = wg % 98;
    int r0 = by * 128, c0 = bx * 128;

    const int srow = tid >> 3;
    const int seg = tid & 7;
    const int sw = seg ^ (srow & 7);

    f32x4 acc[4][4];
#pragma unroll
    for (int m = 0; m < 4; m++)
#pragma unroll
        for (int n = 0; n < 4; n++) acc[m][n] = (f32x4){0.0f, 0.0f, 0.0f, 0.0f};

    for (int ks = 0; ks < 8; ks++) {
        int k0 = ks * 64;
#pragma unroll
        for (int rd = 0; rd < 4; rd++) {
            int row = rd * 32 + srow;
            size_t ga = (((size_t)(r0 + row)) << 9) + k0 + seg * 8;
            size_t gb = (((size_t)(c0 + row)) << 9) + k0 + seg * 8;
            int la = row * 64 + sw * 8;
            *(short8v*)(AhU + la) = *(const short8v*)(xh + ga);
            *(short8v*)(AlU + la) = *(const short8v*)(xl + ga);
            *(short8v*)(BhU + la) = *(const short8v*)(ch + gb);
            *(short8v*)(BlU + la) = *(const short8v*)(cl + gb);
        }
        __syncthreads();
#pragma unroll
        for (int ksub = 0; ksub < 2; ksub++) {
            int segsw = ((ksub * 4 + lkg) ^ (lrow & 7)) * 8;
            short8v afh[4], afl[4], bfh[4], bfl[4];
#pragma unroll
            for (int m = 0; m < 4; m++) {
                int off = (wrbase + m * 16 + lrow) * 64 + segsw;
                afh[m] = *(const short8v*)(AhU + off);
                afl[m] = *(const short8v*)(AlU + off);
            }
#pragma unroll
            for (int n = 0; n < 4; n++) {
                int off = (wcbase + n * 16 + lrow) * 64 + segsw;
                bfh[n] = *(const short8v*)(BhU + off);
                bfl[n] = *(const short8v*)(BlU + off);
            }
#pragma unroll
            for (int m = 0; m < 4; m++)
#pragma unroll
                for (int n = 0; n < 4; n++) {
                    acc[m][n] = __builtin_amdgcn_mfma_f32_16x16x32_bf16(afh[m], bfh[n], acc[m][n], 0, 0, 0);
                    acc[m][n] = __builtin_amdgcn_mfma_f32_16x16x32_bf16(afh[m], bfl[n], acc[m][n], 0, 0, 0);
                    acc[m][n] = __builtin_amdgcn_mfma_f32_16x16x32_bf16(afl[m], bfh[n], acc[m][n], 0, 0, 0);
                }
        }
        __syncthreads();
    }

    float cnv[4];
#pragma unroll
    for (int n = 0; n < 4; n++) cnv[n] = (float)cbn[c0 + wcbase + n * 16 + lrow];

    float* sD = (float*)smem;
    int* sI = (int*)(smem + 32768);
#pragma unroll
    for (int m = 0; m < 4; m++)
#pragma unroll
        for (int v = 0; v < 4; v++) {
            int row = wrbase + m * 16 + lkg * 4 + v;
            float d1 = 1e30f, d2 = 1e30f; int j1 = 0, j2 = 0;
#pragma unroll
            for (int n = 0; n < 4; n++) {
                int code = c0 + wcbase + n * 16 + lrow;
                float d = cnv[n] - 2.0f * acc[m][n][v];
                if (d < d1 || (d == d1 && code < j1)) { d2 = d1; j2 = j1; d1 = d; j1 = code; }
                else if (d < d2 || (d == d2 && code < j2)) { d2 = d; j2 = code; }
            }
            int slot = (wc * 16 + lrow) * 2;
            sD[row * 64 + slot] = d1; sD[row * 64 + slot + 1] = d2;
            sI[row * 64 + slot] = j1; sI[row * 64 + slot + 1] = j2;
        }
    __syncthreads();
    if (tid < 128) {
        float d1 = 1e30f, d2 = 1e30f; int j1 = 0, j2 = 0;
        for (int e = 0; e < 64; e++) {
            int s = (e + tid) & 63;              // rotated scan: conflict-free banks
            float d = sD[tid * 64 + s]; int ix = sI[tid * 64 + s];
            if (d < d1 || (d == d1 && ix < j1)) { d2 = d1; j2 = j1; d1 = d; j1 = ix; }
            else if (d < d2 || (d == d2 && ix < j2)) { d2 = d; j2 = ix; }
        }
        cand[(size_t)bx * NROWS + r0 + tid] =
            make_float4(d1, __int_as_float(j1), d2, __int_as_float(j2));
    }
}

// ---------------- VQ phase 2: merge 64 splits' top-2; flag near-ties; compact list
__global__ __launch_bounds__(256) void k_vq2(const float4* __restrict__ cand,
                                             int* __restrict__ idxbuf,
                                             int* __restrict__ flagbuf,
                                             int* __restrict__ flaglist,
                                             int* __restrict__ nflag, int nrows) {
    int row = blockIdx.x * 256 + threadIdx.x;
    if (row >= nrows) return;
    float d1 = 1e30f, d2 = 1e30f; int j1 = 0, j2 = 0;
    for (int s = 0; s < NSPLIT; s++) {
        float4 c = cand[(size_t)s * nrows + row];
        float dd[2] = {c.x, c.z};
        int ii[2] = {__float_as_int(c.y), __float_as_int(c.w)};
#pragma unroll
        for (int e = 0; e < 2; e++) {
            float d = dd[e]; int ix = ii[e];
            if (d < d1 || (d == d1 && ix < j1)) { d2 = d1; j2 = j1; d1 = d; j1 = ix; }
            else if (d < d2 || (d == d2 && ix < j2)) { d2 = d; j2 = ix; }
        }
    }
    idxbuf[row] = j1;
    int f = (d2 - d1 < VEPS) ? 1 : 0;
    flagbuf[row] = f;
    if (f) {
        int pos = atomicAdd(nflag, 1);
        flaglist[pos] = row;
    }
}

// ---------------- VQ phase 3a: flagged rows x 32 code-slabs; exact fp64 per slab.
__global__ __launch_bounds__(256) void k_vq3a(const float* __restrict__ x,
                                              const float* __restrict__ cbT,
                                              const double* __restrict__ cbn,
                                              const int* __restrict__ flaglist,
                                              const int* __restrict__ nflag,
                                              double* __restrict__ partd,
                                              int* __restrict__ parti) {
    __shared__ __align__(16) float xs[DMODEL];
    __shared__ double sd[256];
    __shared__ int si[256];
    int nf = *nflag;
    int slab = blockIdx.y;
    int tid = threadIdx.x;
    for (int fi = blockIdx.x; fi < nf; fi += gridDim.x) {
        int row = flaglist[fi];
        xs[tid] = x[(size_t)row * DMODEL + tid];
        xs[tid + 256] = x[(size_t)row * DMODEL + tid + 256];
        __syncthreads();
        int c = slab * 256 + tid;
        double a0 = 0.0, a1 = 0.0, a2 = 0.0, a3 = 0.0;
        const float4* xs4 = (const float4*)xs;
#pragma unroll 8
        for (int q = 0; q < DMODEL / 4; q++) {
            float4 xv = xs4[q];
            const float* cp = cbT + (size_t)(q * 4) * KCB + c;
            a0 = fma((double)xv.x, (double)cp[0], a0);
            a1 = fma((double)xv.y, (double)cp[KCB], a1);
            a2 = fma((double)xv.z, (double)cp[2 * KCB], a2);
            a3 = fma((double)xv.w, (double)cp[3 * KCB], a3);
        }
        sd[tid] = cbn[c] - 2.0 * ((a0 + a1) + (a2 + a3));
        si[tid] = c;
        __syncthreads();
        for (int off = 128; off > 0; off >>= 1) {
            if (tid < off) {
                if (sd[tid + off] < sd[tid] ||
                    (sd[tid + off] == sd[tid] && si[tid + off] < si[tid])) {
                    sd[tid] = sd[tid + off]; si[tid] = si[tid + off];
                }
            }
            __syncthreads();
        }
        if (tid == 0) {
            partd[(size_t)row * 32 + slab] = sd[0];
            parti[(size_t)row * 32 + slab] = si[0];
        }
        __syncthreads();
    }
}

// ---------------- VQ phase 3b: merge 32 slab partials per flagged row; write outputs
__global__ __launch_bounds__(256) void k_vq3b(const float* __restrict__ cb,
                                              const int* __restrict__ idxbuf,
                                              const int* __restrict__ flagbuf,
                                              const double* __restrict__ partd,
                                              const int* __restrict__ parti,
                                              float* __restrict__ outq,
                                              float* __restrict__ outi) {
    int row = blockIdx.x;
    int tid = threadIdx.x;
    __shared__ int bestsh;
    int best = idxbuf[row];
    if (flagbuf[row]) {
        if (tid == 0) {
            double bd = partd[(size_t)row * 32];
            int bi = parti[(size_t)row * 32];
            for (int s = 1; s < 32; s++) {
                double d = partd[(size_t)row * 32 + s];
                int ix = parti[(size_t)row * 32 + s];
                if (d < bd || (d == bd && ix < bi)) { bd = d; bi = ix; }
            }
            bestsh = bi;
        }
        __syncthreads();
        best = bestsh;
    }
    const float* crow = cb + (size_t)best * DMODEL;
    outq[(size_t)row * DMODEL + tid] = crow[tid];
    outq[(size_t)row * DMODEL + tid + 256] = crow[tid + 256];
    if (tid == 0) outi[row] = (float)best;
}

extern "C" void kernel_launch(void* const* d_in, const int* in_sizes, int n_in,
                              void* d_out, int out_size, void* d_ws, size_t ws_size,
                              hipStream_t stream) {
    const float* motion = (const float*)d_in[0];
    const float* conv_w = (const float*)d_in[1];
    const float* conv_b = (const float*)d_in[2];
    const float* wqkv   = (const float*)d_in[3];
    const float* bqkv   = (const float*)d_in[4];
    const float* wo     = (const float*)d_in[5];
    const float* bo     = (const float*)d_in[6];
    const float* ln1g   = (const float*)d_in[7];
    const float* ln1b   = (const float*)d_in[8];
    const float* ln2g   = (const float*)d_in[9];
    const float* ln2b   = (const float*)d_in[10];
    const float* w1     = (const float*)d_in[11];
    const float* b1     = (const float*)d_in[12];
    const float* w2     = (const float*)d_in[13];
    const float* b2     = (const float*)d_in[14];
    const float* cb     = (const float*)d_in[15];

    const size_t SZc = (size_t)25088 * DMODEL;
    float* wsf = (float*)d_ws;
    float*  S0  = wsf + 0 * SZc;
    float*  S1  = wsf + 1 * SZc;
    float*  S2  = wsf + 2 * SZc;
    float*  S3  = wsf + 3 * SZc;
    char* p = (char*)(wsf + 4 * SZc);
    unsigned short* wh = (unsigned short*)p;   p += (size_t)786432 * 2;
    unsigned short* wm = (unsigned short*)p;   p += (size_t)786432 * 2;
    unsigned short* wl = (unsigned short*)p;   p += (size_t)786432 * 2;
    double* cbn    = (double*)p;               p += KCB * 8;
    int*   idxbuf  = (int*)p;                  p += NROWS * 4;
    int*   flagbuf = (int*)p;                  p += NROWS * 4;
    int*   flaglist= (int*)p;                  p += NROWS * 4;
    int*   nflag   = (int*)p;                  p += 256;
    double* partd  = (double*)p;               p += (size_t)NROWS * 32 * 8;
    int*   parti   = (int*)p;                  p += (size_t)NROWS * 32 * 4;

    k_cbn<<<dim3(KCB), dim3(64), 0, stream>>>(cb, cbn);

    const float* xin = motion;
    int Tin = 196;
    for (int l = 0; l < 2; l++) {
        int Tout = Tin / 2;            // 98, then 49
        int M = BBATCH * Tout;         // 25088, then 12544
        const float* wq = wqkv + (size_t)l * DMODEL * 3 * DMODEL;
        const float* bq = bqkv + (size_t)l * 3 * DMODEL;

        // conv (fused gather + exact fp64 GELU epilogue)
        k_wsplit3_conv<<<dim3(3072), dim3(256), 0, stream>>>(
            conv_w + (size_t)l * DMODEL * DMODEL * 3, wh, wm, wl);
        k_gemm6<1, 1><<<dim3(4, M / 128), dim3(256), 0, stream>>>(
            xin, DMODEL, wh, wm, wl, conv_b + l * DMODEL, S0, DMODEL,
            3 * DMODEL, Tin, Tout);
        // qkv
        float* qkvdst[3] = {S1, S2, S3};
        for (int s = 0; s < 3; s++) {
            k_wsplit3Tt<<<dim3(8, 8), dim3(256), 0, stream>>>(
                wq + s * DMODEL, 3 * DMODEL, DMODEL, wh, wm, wl);
            k_gemm6<0, 0><<<dim3(4, M / 128), dim3(256), 0, stream>>>(
                S0, DMODEL, wh, wm, wl, bq + s * DMODEL, qkvdst[s], DMODEL,
                DMODEL, 1, 1);
        }
        k_attn<<<dim3(NHEAD, BBATCH), dim3(256), 0, stream>>>(S1, S2, S3, S1, Tout);
        // wo
        k_wsplit3Tt<<<dim3(8, 8), dim3(256), 0, stream>>>(
            wo + (size_t)l * DMODEL * DMODEL, DMODEL, DMODEL, wh, wm, wl);
        k_gemm6<0, 0><<<dim3(4, M / 128), dim3(256), 0, stream>>>(
            S1, DMODEL, wh, wm, wl, bo + l * DMODEL, S2, DMODEL, DMODEL, 1, 1);
        k_ln<<<dim3(M), dim3(128), 0, stream>>>(S0, S2, ln1g + l * DMODEL, ln1b + l * DMODEL, S3);
        // ffn
        k_wsplit3Tt<<<dim3(8, 16), dim3(256), 0, stream>>>(
            w1 + (size_t)l * DMODEL * DFFN, DFFN, DMODEL, wh, wm, wl);
        k_gemm6<2, 0><<<dim3(8, M / 128), dim3(256), 0, stream>>>(
            S3, DMODEL, wh, wm, wl, b1 + l * DFFN, S1, DFFN, DMODEL, 1, 1);
        k_wsplit3Tt<<<dim3(16, 8), dim3(256), 0, stream>>>(
            w2 + (size_t)l * DFFN * DMODEL, DMODEL, DFFN, wh, wm, wl);
        k_gemm6<0, 0><<<dim3(4, M / 128), dim3(256), 0, stream>>>(
            S1, DFFN, wh, wm, wl, b2 + l * DMODEL, S0, DMODEL, DFFN, 1, 1);
        k_ln<<<dim3(M), dim3(128), 0, stream>>>(S3, S0, ln2g + l * DMODEL, ln2b + l * DMODEL, S1);

        xin = S1;
        Tin = Tout;
    }

    // ---- VQ: split x (S1) and codebook to bf16 hi/lo in freed scratch (S2, S3).
    // cand (64 splits x NROWS float4 = 12.85 MB) lives in freed S0.
    unsigned short* xh = (unsigned short*)S2;
    unsigned short* xl = xh + (size_t)NROWS * DMODEL;
    unsigned short* chb = (unsigned short*)S3;
    unsigned short* clb = chb + (size_t)KCB * DMODEL;
    float4* cand = (float4*)S0;
    k_split<<<dim3(NROWS * DMODEL / 4 / 256), dim3(256), 0, stream>>>(S1, xh, xl,
                                                                      NROWS * DMODEL / 4);
    k_split<<<dim3(KCB * DMODEL / 4 / 256), dim3(256), 0, stream>>>(cb, chb, clb,
                                                                    KCB * DMODEL / 4);

    float* outq = (float*)d_out;
    float* outi = outq + (size_t)NROWS * DMODEL;
    hipMemsetAsync(nflag, 0, sizeof(int), stream);
    k_vq1m<<<dim3(98 * NSPLIT), dim3(256), 0, stream>>>(xh, xl, chb, clb, cbn, cand);
    k_vq2<<<dim3(49), dim3(256), 0, stream>>>(cand, idxbuf, flagbuf, flaglist, nflag, NROWS);
    // cbT overwrites chb/clb region (dead after vq1m) — stream order guarantees safety
    float* cbT = (float*)S3;
    k_cbT<<<dim3(KCB / 64, DMODEL / 64), dim3(256), 0, stream>>>(cb, cbT);
    k_vq3a<<<dim3(256, 32), dim3(256), 0, stream>>>(S1, cbT, cbn, flaglist, nflag,
                                                    partd, parti);
    k_vq3b<<<dim3(NROWS), dim3(256), 0, stream>>>(cb, idxbuf, flagbuf, partd, parti,
                                                  outq, outi);
}